// Round 2
// baseline (3924.252 us; speedup 1.0000x reference)
//
#include <hip/hip_runtime.h>
#include <hip/hip_bf16.h>

// Problem constants (MambaMinimalBlock): B=4, L=2048, D_MODEL=1024,
// D_STATE=16, D_CONV=4, D_INNER=2048, BL = B*L = 8192.
// All inputs/outputs fp32.
//
// Workspace budget note: round-1 layout used 269 MB and core-dumped
// (suspected ws overflow). This layout uses 202.4 MB:
//   buf0 [8192,2048] : xi, then delta, then y (in-place)   64 MB
//   buf1 [8192,2048] : z                                    64 MB
//   buf2 [8192,2048] : xc                                   64 MB
//   bc   [8192,32]                                           1 MB

#define TILE_M 128
#define TILE_N 128
#define TILE_K 8

__device__ __forceinline__ float softplus_f(float x) {
    return fmaxf(x, 0.f) + __logf(1.f + __expf(-fabsf(x)));
}

__device__ __forceinline__ float silu_f(float x) {
    return x / (1.f + __expf(-x));
}

// C[M,N] = A[M,K] * B[N,K]^T   (both operands K-contiguous, "NT" GEMM)
// EPI: 0 = none, 1 = softplus(v + bias[col])
// GUARD: bounds-check N (only needed for the tiny x_proj GEMM, N=32)
template <int EPI, bool GUARD>
__global__ __launch_bounds__(256)
void gemm_nt(const float* __restrict__ A, const float* __restrict__ Bm,
             const float* __restrict__ bias, float* __restrict__ C,
             int M, int N, int K)
{
    __shared__ float As[TILE_K][TILE_M + 4];
    __shared__ float Bs[TILE_K][TILE_N + 4];

    const int tid  = threadIdx.x;
    const int row0 = blockIdx.y * TILE_M;
    const int col0 = blockIdx.x * TILE_N;
    const int tm   = (tid >> 4) * 8;   // 0..120, m-offset of 8x8 microtile
    const int tn   = (tid & 15) * 8;   // 0..120, n-offset
    const int lr   = tid >> 1;         // 0..127 staging row
    const int lk   = (tid & 1) * 4;    // 0 or 4 staging k-offset

    const float* Ag = A + (size_t)(row0 + lr) * K + lk;
    const bool bok  = (!GUARD) || ((col0 + lr) < N);
    const float* Bg = Bm + (size_t)(bok ? (col0 + lr) : 0) * K + lk;

    float acc[8][8];
#pragma unroll
    for (int i = 0; i < 8; ++i)
#pragma unroll
        for (int j = 0; j < 8; ++j) acc[i][j] = 0.f;

    for (int k0 = 0; k0 < K; k0 += TILE_K) {
        float4 av = *(const float4*)(Ag + k0);
        float4 bv = bok ? *(const float4*)(Bg + k0) : make_float4(0.f, 0.f, 0.f, 0.f);
        __syncthreads();
        As[lk + 0][lr] = av.x; As[lk + 1][lr] = av.y;
        As[lk + 2][lr] = av.z; As[lk + 3][lr] = av.w;
        Bs[lk + 0][lr] = bv.x; Bs[lk + 1][lr] = bv.y;
        Bs[lk + 2][lr] = bv.z; Bs[lk + 3][lr] = bv.w;
        __syncthreads();
#pragma unroll
        for (int kk = 0; kk < TILE_K; ++kk) {
            float a[8], b[8];
            *(float4*)&a[0] = *(const float4*)&As[kk][tm];
            *(float4*)&a[4] = *(const float4*)&As[kk][tm + 4];
            *(float4*)&b[0] = *(const float4*)&Bs[kk][tn];
            *(float4*)&b[4] = *(const float4*)&Bs[kk][tn + 4];
#pragma unroll
            for (int i = 0; i < 8; ++i)
#pragma unroll
                for (int j = 0; j < 8; ++j)
                    acc[i][j] = fmaf(a[i], b[j], acc[i][j]);
        }
    }

#pragma unroll
    for (int i = 0; i < 8; ++i) {
        const int row = row0 + tm + i;
        float* Crow = C + (size_t)row * N;
        if (EPI == 1) {
#pragma unroll
            for (int j = 0; j < 8; ++j)
                acc[i][j] = softplus_f(acc[i][j] + bias[col0 + tn + j]);
        }
        if (GUARD) {
#pragma unroll
            for (int j = 0; j < 8; ++j) {
                const int col = col0 + tn + j;
                if (col < N) Crow[col] = acc[i][j];
            }
        } else {
            float4 v0 = make_float4(acc[i][0], acc[i][1], acc[i][2], acc[i][3]);
            float4 v1 = make_float4(acc[i][4], acc[i][5], acc[i][6], acc[i][7]);
            *(float4*)&Crow[col0 + tn]     = v0;
            *(float4*)&Crow[col0 + tn + 4] = v1;
        }
    }
}

// Depthwise causal conv1d (4 taps, left pad 3) + bias + silu.
// Reads xi [8192,2048], writes xc [8192,2048].
__global__ __launch_bounds__(256)
void conv_silu_kernel(const float* __restrict__ xi, const float* __restrict__ cw,
                      const float* __restrict__ cb, float* __restrict__ xc)
{
    const int idx = blockIdx.x * 256 + threadIdx.x;   // 8192*512 threads
    const int e   = (idx & 511) << 2;                 // channel, step 4
    const int row = idx >> 9;                         // b*L + l
    const int l   = row & 2047;

    const float4 w0 = *(const float4*)(cw + (size_t)(e + 0) * 4);
    const float4 w1 = *(const float4*)(cw + (size_t)(e + 1) * 4);
    const float4 w2 = *(const float4*)(cw + (size_t)(e + 2) * 4);
    const float4 w3 = *(const float4*)(cw + (size_t)(e + 3) * 4);

    float4 acc = *(const float4*)(cb + e);

    if (l >= 3) {
        float4 v = *(const float4*)(xi + (size_t)(row - 3) * 2048 + e);
        acc.x = fmaf(v.x, w0.x, acc.x); acc.y = fmaf(v.y, w1.x, acc.y);
        acc.z = fmaf(v.z, w2.x, acc.z); acc.w = fmaf(v.w, w3.x, acc.w);
    }
    if (l >= 2) {
        float4 v = *(const float4*)(xi + (size_t)(row - 2) * 2048 + e);
        acc.x = fmaf(v.x, w0.y, acc.x); acc.y = fmaf(v.y, w1.y, acc.y);
        acc.z = fmaf(v.z, w2.y, acc.z); acc.w = fmaf(v.w, w3.y, acc.w);
    }
    if (l >= 1) {
        float4 v = *(const float4*)(xi + (size_t)(row - 1) * 2048 + e);
        acc.x = fmaf(v.x, w0.z, acc.x); acc.y = fmaf(v.y, w1.z, acc.y);
        acc.z = fmaf(v.z, w2.z, acc.z); acc.w = fmaf(v.w, w3.z, acc.w);
    }
    {
        float4 v = *(const float4*)(xi + (size_t)row * 2048 + e);
        acc.x = fmaf(v.x, w0.w, acc.x); acc.y = fmaf(v.y, w1.w, acc.y);
        acc.z = fmaf(v.z, w2.w, acc.z); acc.w = fmaf(v.w, w3.w, acc.w);
    }

    acc.x = silu_f(acc.x); acc.y = silu_f(acc.y);
    acc.z = silu_f(acc.z); acc.w = silu_f(acc.w);
    *(float4*)(xc + (size_t)row * 2048 + e) = acc;
}

// Selective scan. One lane per (b, d, s); 16-lane shfl_xor reduction for y.
// Fuses + xc*D and * silu(z). Writes y IN PLACE over the delta buffer
// (lane-group reads delta[row,d] via prefetch before lane s==0 overwrites it;
// write at row l vs reads at row l+1 — disjoint addresses, single group owns
// column (b,d), so no races).
__global__ __launch_bounds__(256)
void scan_kernel(const float* __restrict__ zbuf, const float* __restrict__ xc,
                 const float* __restrict__ dbuf, const float* __restrict__ bcbuf,
                 const float* __restrict__ A_log, const float* __restrict__ Dp,
                 float* __restrict__ ybuf)
{
    const int gid = blockIdx.x * 256 + threadIdx.x;  // 131072 lanes
    const int s   = gid & 15;
    const int ch  = gid >> 4;        // 0..8191
    const int d   = ch & 2047;
    const int b   = ch >> 11;

    const float Aval = -__expf(A_log[(d << 4) + s]);
    const float Dv   = Dp[d];

    const size_t rbase = (size_t)b * 2048;           // first row of this batch
    const float* dptr = dbuf  + rbase * 2048 + d;
    const float* xptr = xc    + rbase * 2048 + d;
    const float* bptr = bcbuf + rbase * 32 + s;
    const float* zptr = zbuf  + rbase * 2048 + d;
    float*       yptr = ybuf  + rbase * 2048 + d;

    float h = 0.f;
    float dt = dptr[0], xv = xptr[0], Bv = bptr[0], Cv = bptr[16];

    for (int l = 0; l < 2048; ++l) {
        float dtn = 0.f, xvn = 0.f, Bvn = 0.f, Cvn = 0.f;
        if (l + 1 < 2048) {              // depth-1 prefetch
            const size_t o = (size_t)(l + 1);
            dtn = dptr[o * 2048];
            xvn = xptr[o * 2048];
            Bvn = bptr[o * 32];
            Cvn = bptr[o * 32 + 16];
        }
        h = __expf(dt * Aval) * h + (dt * Bv) * xv;
        float p = h * Cv;
        p += __shfl_xor(p, 1, 16);
        p += __shfl_xor(p, 2, 16);
        p += __shfl_xor(p, 4, 16);
        p += __shfl_xor(p, 8, 16);
        if (s == 0) {
            const float zv = zptr[(size_t)l * 2048];
            const float y  = p + Dv * xv;
            yptr[(size_t)l * 2048] = y * silu_f(zv);
        }
        dt = dtn; xv = xvn; Bv = Bvn; Cv = Cvn;
    }
}

extern "C" void kernel_launch(void* const* d_in, const int* in_sizes, int n_in,
                              void* d_out, int out_size, void* d_ws, size_t ws_size,
                              hipStream_t stream)
{
    const float* x          = (const float*)d_in[0];  // [4,2048,1024]
    const float* in_proj_w  = (const float*)d_in[1];  // [4096,1024]
    const float* conv_w     = (const float*)d_in[2];  // [2048,1,4]
    const float* conv_b     = (const float*)d_in[3];  // [2048]
    const float* x_proj_w   = (const float*)d_in[4];  // [32,2048]
    const float* dt_proj_w  = (const float*)d_in[5];  // [2048,2048]
    const float* dt_proj_b  = (const float*)d_in[6];  // [2048]
    const float* A_log      = (const float*)d_in[7];  // [2048,16]
    const float* Dp         = (const float*)d_in[8];  // [2048]
    const float* out_proj_w = (const float*)d_in[9];  // [1024,2048]
    float* out = (float*)d_out;                       // [4,2048,1024]

    // Workspace layout (floats), 202.4 MB total:
    const long long NBL = 16777216LL;   // 8192*2048
    float* buf0 = (float*)d_ws;         // xi -> delta -> y
    float* buf1 = buf0 + NBL;           // z
    float* buf2 = buf1 + NBL;           // xc
    float* bc   = buf2 + NBL;           // [8192,32]

    const dim3 blk(256);

    // 1a) xi = x @ in_proj_w[0:2048]^T       M=8192 N=2048 K=1024
    gemm_nt<0, false><<<dim3(2048 / TILE_N, 8192 / TILE_M), blk, 0, stream>>>(
        x, in_proj_w, nullptr, buf0, 8192, 2048, 1024);
    // 1b) z  = x @ in_proj_w[2048:4096]^T
    gemm_nt<0, false><<<dim3(2048 / TILE_N, 8192 / TILE_M), blk, 0, stream>>>(
        x, in_proj_w + 2048LL * 1024, nullptr, buf1, 8192, 2048, 1024);

    // 2) xc = silu(causal_conv(xi) + b)
    conv_silu_kernel<<<dim3(8192 * 512 / 256), blk, 0, stream>>>(buf0, conv_w, conv_b, buf2);

    // 3) delta = softplus(xc @ dt_proj_w^T + dt_proj_b)   M=8192 N=2048 K=2048
    //    (overwrites buf0 — xi is dead after conv)
    gemm_nt<1, false><<<dim3(2048 / TILE_N, 8192 / TILE_M), blk, 0, stream>>>(
        buf2, dt_proj_w, dt_proj_b, buf0, 8192, 2048, 2048);

    // 4) bc = xc @ x_proj_w^T            M=8192 N=32 K=2048 (guarded)
    gemm_nt<0, true><<<dim3(1, 8192 / TILE_M), blk, 0, stream>>>(
        buf2, x_proj_w, nullptr, bc, 8192, 32, 2048);

    // 5) selective scan (y overwrites delta in buf0); fuses +xc*D and *silu(z)
    scan_kernel<<<dim3(131072 / 256), blk, 0, stream>>>(
        buf1, buf2, buf0, bc, A_log, Dp, buf0);

    // 6) out = y @ out_proj_w^T          M=8192 N=1024 K=2048
    gemm_nt<0, false><<<dim3(1024 / TILE_N, 8192 / TILE_M), blk, 0, stream>>>(
        buf0, out_proj_w, nullptr, out, 8192, 1024, 2048);
}

// Round 3
// 3069.205 us; speedup vs baseline: 1.2786x; 1.2786x over previous
//
#include <hip/hip_runtime.h>
#include <hip/hip_bf16.h>

// Problem constants (MambaMinimalBlock): B=4, L=2048, D_MODEL=1024,
// D_STATE=16, D_CONV=4, D_INNER=2048, BL = B*L = 8192.
// All inputs/outputs fp32.
//
// Workspace layout (202.4 MB):
//   buf0 [8192,2048] : xi, then delta, then y (in-place)   64 MB
//   buf1 [8192,2048] : z                                    64 MB
//   buf2 [8192,2048] : xc                                   64 MB
//   bc   [8192,32]                                           1 MB

#define TILE_M 128
#define TILE_N 128
#define TILE_K 8

__device__ __forceinline__ float softplus_f(float x) {
    return fmaxf(x, 0.f) + __logf(1.f + __expf(-fabsf(x)));
}

__device__ __forceinline__ float silu_f(float x) {
    return x / (1.f + __expf(-x));
}

// C[M,N] = A[M,K] * B[N,K]^T   (both operands K-contiguous, "NT" GEMM)
// EPI: 0 = none, 1 = softplus(v + bias[col])
// GUARD: bounds-check N (only needed for the tiny x_proj GEMM, N=32)
template <int EPI, bool GUARD>
__global__ __launch_bounds__(256)
void gemm_nt(const float* __restrict__ A, const float* __restrict__ Bm,
             const float* __restrict__ bias, float* __restrict__ C,
             int M, int N, int K)
{
    __shared__ float As[TILE_K][TILE_M + 4];
    __shared__ float Bs[TILE_K][TILE_N + 4];

    const int tid  = threadIdx.x;
    const int row0 = blockIdx.y * TILE_M;
    const int col0 = blockIdx.x * TILE_N;
    const int tm   = (tid >> 4) * 8;   // 0..120, m-offset of 8x8 microtile
    const int tn   = (tid & 15) * 8;   // 0..120, n-offset
    const int lr   = tid >> 1;         // 0..127 staging row
    const int lk   = (tid & 1) * 4;    // 0 or 4 staging k-offset

    const float* Ag = A + (size_t)(row0 + lr) * K + lk;
    const bool bok  = (!GUARD) || ((col0 + lr) < N);
    const float* Bg = Bm + (size_t)(bok ? (col0 + lr) : 0) * K + lk;

    float acc[8][8];
#pragma unroll
    for (int i = 0; i < 8; ++i)
#pragma unroll
        for (int j = 0; j < 8; ++j) acc[i][j] = 0.f;

    for (int k0 = 0; k0 < K; k0 += TILE_K) {
        float4 av = *(const float4*)(Ag + k0);
        float4 bv = bok ? *(const float4*)(Bg + k0) : make_float4(0.f, 0.f, 0.f, 0.f);
        __syncthreads();
        As[lk + 0][lr] = av.x; As[lk + 1][lr] = av.y;
        As[lk + 2][lr] = av.z; As[lk + 3][lr] = av.w;
        Bs[lk + 0][lr] = bv.x; Bs[lk + 1][lr] = bv.y;
        Bs[lk + 2][lr] = bv.z; Bs[lk + 3][lr] = bv.w;
        __syncthreads();
#pragma unroll
        for (int kk = 0; kk < TILE_K; ++kk) {
            float a[8], b[8];
            *(float4*)&a[0] = *(const float4*)&As[kk][tm];
            *(float4*)&a[4] = *(const float4*)&As[kk][tm + 4];
            *(float4*)&b[0] = *(const float4*)&Bs[kk][tn];
            *(float4*)&b[4] = *(const float4*)&Bs[kk][tn + 4];
#pragma unroll
            for (int i = 0; i < 8; ++i)
#pragma unroll
                for (int j = 0; j < 8; ++j)
                    acc[i][j] = fmaf(a[i], b[j], acc[i][j]);
        }
    }

#pragma unroll
    for (int i = 0; i < 8; ++i) {
        const int row = row0 + tm + i;
        float* Crow = C + (size_t)row * N;
        if (EPI == 1) {
#pragma unroll
            for (int j = 0; j < 8; ++j)
                acc[i][j] = softplus_f(acc[i][j] + bias[col0 + tn + j]);
        }
        if (GUARD) {
#pragma unroll
            for (int j = 0; j < 8; ++j) {
                const int col = col0 + tn + j;
                if (col < N) Crow[col] = acc[i][j];
            }
        } else {
            float4 v0 = make_float4(acc[i][0], acc[i][1], acc[i][2], acc[i][3]);
            float4 v1 = make_float4(acc[i][4], acc[i][5], acc[i][6], acc[i][7]);
            *(float4*)&Crow[col0 + tn]     = v0;
            *(float4*)&Crow[col0 + tn + 4] = v1;
        }
    }
}

// Depthwise causal conv1d (4 taps, left pad 3) + bias + silu.
// Reads xi [8192,2048], writes xc [8192,2048].
__global__ __launch_bounds__(256)
void conv_silu_kernel(const float* __restrict__ xi, const float* __restrict__ cw,
                      const float* __restrict__ cb, float* __restrict__ xc)
{
    const int idx = blockIdx.x * 256 + threadIdx.x;   // 8192*512 threads
    const int e   = (idx & 511) << 2;                 // channel, step 4
    const int row = idx >> 9;                         // b*L + l
    const int l   = row & 2047;

    const float4 w0 = *(const float4*)(cw + (size_t)(e + 0) * 4);
    const float4 w1 = *(const float4*)(cw + (size_t)(e + 1) * 4);
    const float4 w2 = *(const float4*)(cw + (size_t)(e + 2) * 4);
    const float4 w3 = *(const float4*)(cw + (size_t)(e + 3) * 4);

    float4 acc = *(const float4*)(cb + e);

    if (l >= 3) {
        float4 v = *(const float4*)(xi + (size_t)(row - 3) * 2048 + e);
        acc.x = fmaf(v.x, w0.x, acc.x); acc.y = fmaf(v.y, w1.x, acc.y);
        acc.z = fmaf(v.z, w2.x, acc.z); acc.w = fmaf(v.w, w3.x, acc.w);
    }
    if (l >= 2) {
        float4 v = *(const float4*)(xi + (size_t)(row - 2) * 2048 + e);
        acc.x = fmaf(v.x, w0.y, acc.x); acc.y = fmaf(v.y, w1.y, acc.y);
        acc.z = fmaf(v.z, w2.y, acc.z); acc.w = fmaf(v.w, w3.y, acc.w);
    }
    if (l >= 1) {
        float4 v = *(const float4*)(xi + (size_t)(row - 1) * 2048 + e);
        acc.x = fmaf(v.x, w0.z, acc.x); acc.y = fmaf(v.y, w1.z, acc.y);
        acc.z = fmaf(v.z, w2.z, acc.z); acc.w = fmaf(v.w, w3.z, acc.w);
    }
    {
        float4 v = *(const float4*)(xi + (size_t)row * 2048 + e);
        acc.x = fmaf(v.x, w0.w, acc.x); acc.y = fmaf(v.y, w1.w, acc.y);
        acc.z = fmaf(v.z, w2.w, acc.z); acc.w = fmaf(v.w, w3.w, acc.w);
    }

    acc.x = silu_f(acc.x); acc.y = silu_f(acc.y);
    acc.z = silu_f(acc.z); acc.w = silu_f(acc.w);
    *(float4*)(xc + (size_t)row * 2048 + e) = acc;
}

// Selective scan, latency-optimized. One lane per (b, d, s); 16-lane
// shfl_xor reduction for y. Time loop is blocked by SCH with double-buffered
// register prefetch of ALL streams (incl. z — previously its load stalled
// the wave inside the s==0 branch every iteration). Per block: ~80
// independent loads issued back-to-back, then 16 steps computed from the
// previous block's registers → one HBM latency amortized over 16 steps.
// y overwrites delta in place (writes trail the reads by a full block; a
// single lane-group owns column (b,d), so no races).
#define SCH 16

__global__ __launch_bounds__(256)
void scan_kernel(const float* __restrict__ zbuf, const float* __restrict__ xc,
                 const float* __restrict__ dbuf, const float* __restrict__ bcbuf,
                 const float* __restrict__ A_log, const float* __restrict__ Dp,
                 float* __restrict__ ybuf)
{
    const int gid = blockIdx.x * 256 + threadIdx.x;  // 131072 lanes
    const int s   = gid & 15;
    const int ch  = gid >> 4;        // 0..8191
    const int d   = ch & 2047;
    const int b   = ch >> 11;

    const float Aval = -__expf(A_log[(d << 4) + s]);
    const float Dv   = Dp[d];

    const size_t rbase = (size_t)b * 2048;           // first row of this batch
    const float* dptr = dbuf  + rbase * 2048 + d;
    const float* xptr = xc    + rbase * 2048 + d;
    const float* bptr = bcbuf + rbase * 32 + s;
    const float* zptr = zbuf  + rbase * 2048 + d;
    float*       yptr = ybuf  + rbase * 2048 + d;

    float cdt[SCH], cxv[SCH], cBv[SCH], cCv[SCH], czv[SCH];
#pragma unroll
    for (int j = 0; j < SCH; ++j) {
        const size_t o = (size_t)j;
        cdt[j] = dptr[o * 2048];
        cxv[j] = xptr[o * 2048];
        cBv[j] = bptr[o * 32];
        cCv[j] = bptr[o * 32 + 16];
        czv[j] = zptr[o * 2048];
    }

    float h = 0.f;
    for (int l0 = 0; l0 < 2048; l0 += SCH) {
        float ndt[SCH], nxv[SCH], nBv[SCH], nCv[SCH], nzv[SCH];
        const bool more = (l0 + SCH) < 2048;
        if (more) {
#pragma unroll
            for (int j = 0; j < SCH; ++j) {
                const size_t o = (size_t)(l0 + SCH + j);
                ndt[j] = dptr[o * 2048];
                nxv[j] = xptr[o * 2048];
                nBv[j] = bptr[o * 32];
                nCv[j] = bptr[o * 32 + 16];
                nzv[j] = zptr[o * 2048];
            }
        }
#pragma unroll
        for (int j = 0; j < SCH; ++j) {
            h = __expf(cdt[j] * Aval) * h + (cdt[j] * cBv[j]) * cxv[j];
            float p = h * cCv[j];
            p += __shfl_xor(p, 1, 16);
            p += __shfl_xor(p, 2, 16);
            p += __shfl_xor(p, 4, 16);
            p += __shfl_xor(p, 8, 16);
            if (s == 0) {
                const float y = p + Dv * cxv[j];
                yptr[(size_t)(l0 + j) * 2048] = y * silu_f(czv[j]);
            }
        }
        if (more) {
#pragma unroll
            for (int j = 0; j < SCH; ++j) {
                cdt[j] = ndt[j]; cxv[j] = nxv[j]; cBv[j] = nBv[j];
                cCv[j] = nCv[j]; czv[j] = nzv[j];
            }
        }
    }
}

extern "C" void kernel_launch(void* const* d_in, const int* in_sizes, int n_in,
                              void* d_out, int out_size, void* d_ws, size_t ws_size,
                              hipStream_t stream)
{
    const float* x          = (const float*)d_in[0];  // [4,2048,1024]
    const float* in_proj_w  = (const float*)d_in[1];  // [4096,1024]
    const float* conv_w     = (const float*)d_in[2];  // [2048,1,4]
    const float* conv_b     = (const float*)d_in[3];  // [2048]
    const float* x_proj_w   = (const float*)d_in[4];  // [32,2048]
    const float* dt_proj_w  = (const float*)d_in[5];  // [2048,2048]
    const float* dt_proj_b  = (const float*)d_in[6];  // [2048]
    const float* A_log      = (const float*)d_in[7];  // [2048,16]
    const float* Dp         = (const float*)d_in[8];  // [2048]
    const float* out_proj_w = (const float*)d_in[9];  // [1024,2048]
    float* out = (float*)d_out;                       // [4,2048,1024]

    // Workspace layout (floats), 202.4 MB total:
    const long long NBL = 16777216LL;   // 8192*2048
    float* buf0 = (float*)d_ws;         // xi -> delta -> y
    float* buf1 = buf0 + NBL;           // z
    float* buf2 = buf1 + NBL;           // xc
    float* bc   = buf2 + NBL;           // [8192,32]

    const dim3 blk(256);

    // 1a) xi = x @ in_proj_w[0:2048]^T       M=8192 N=2048 K=1024
    gemm_nt<0, false><<<dim3(2048 / TILE_N, 8192 / TILE_M), blk, 0, stream>>>(
        x, in_proj_w, nullptr, buf0, 8192, 2048, 1024);
    // 1b) z  = x @ in_proj_w[2048:4096]^T
    gemm_nt<0, false><<<dim3(2048 / TILE_N, 8192 / TILE_M), blk, 0, stream>>>(
        x, in_proj_w + 2048LL * 1024, nullptr, buf1, 8192, 2048, 1024);

    // 2) xc = silu(causal_conv(xi) + b)
    conv_silu_kernel<<<dim3(8192 * 512 / 256), blk, 0, stream>>>(buf0, conv_w, conv_b, buf2);

    // 3) delta = softplus(xc @ dt_proj_w^T + dt_proj_b)   M=8192 N=2048 K=2048
    //    (overwrites buf0 — xi is dead after conv)
    gemm_nt<1, false><<<dim3(2048 / TILE_N, 8192 / TILE_M), blk, 0, stream>>>(
        buf2, dt_proj_w, dt_proj_b, buf0, 8192, 2048, 2048);

    // 4) bc = xc @ x_proj_w^T            M=8192 N=32 K=2048 (guarded)
    gemm_nt<0, true><<<dim3(1, 8192 / TILE_M), blk, 0, stream>>>(
        buf2, x_proj_w, nullptr, bc, 8192, 32, 2048);

    // 5) selective scan (y overwrites delta in buf0); fuses +xc*D and *silu(z)
    scan_kernel<<<dim3(131072 / 256), blk, 0, stream>>>(
        buf1, buf2, buf0, bc, A_log, Dp, buf0);

    // 6) out = y @ out_proj_w^T          M=8192 N=1024 K=2048
    gemm_nt<0, false><<<dim3(1024 / TILE_N, 8192 / TILE_M), blk, 0, stream>>>(
        buf0, out_proj_w, nullptr, out, 8192, 1024, 2048);
}

// Round 4
// 1488.833 us; speedup vs baseline: 2.6358x; 2.0615x over previous
//
#include <hip/hip_runtime.h>
#include <hip/hip_bf16.h>

// MambaMinimalBlock: B=4, L=2048, D_MODEL=1024, D_STATE=16, D_CONV=4,
// D_INNER=2048, BL=8192. fp32 in/out.
//
// Strategy: GEMMs on bf16 MFMA with weight-split (W = Whi + Wlo, two bf16
// planes; 2 MFMA per fragment pair) and plain-bf16 activations. Activation
// quantization error random-walks across K (est. absmax contribution ~1e-3
// vs 5.6e-3 threshold); weights effectively fp32-precise.
//
// Workspace (201 MB; r1 showed 269.5e6 B crashes => ws likely 256 MiB):
//   XI   [8192,2048] bf16  32 MB   (xi; later reused as Y')
//   Z    [8192,2048] bf16  32 MB
//   XC2  [8192,2048] bf16  32 MB
//   DELTA[8192,2048] f32   64 MB   (first 16 MB hosts X' bf16 before dt GEMM)
//   W planes: in 8+8, dt 8+8, out 4+4 = 40 MB
//   BC   [8192,32]  f32     1 MB

typedef float  f32x4  __attribute__((ext_vector_type(4)));
typedef short  bf16x8 __attribute__((ext_vector_type(8)));

__device__ __forceinline__ ushort f2bf(float f) {
    uint u = __float_as_uint(f);
    u += 0x7FFF + ((u >> 16) & 1);          // RNE
    return (ushort)(u >> 16);
}
__device__ __forceinline__ float bf2f(ushort h) {
    return __uint_as_float((uint)h << 16);
}
__device__ __forceinline__ float softplus_f(float x) {
    return fmaxf(x, 0.f) + __logf(1.f + __expf(-fabsf(x)));
}
__device__ __forceinline__ float silu_f(float x) {
    return x / (1.f + __expf(-x));
}

// fp32 -> (hi, lo) bf16 planes. n4 = element count / 4.
__global__ __launch_bounds__(256)
void split_w_kernel(const float* __restrict__ src, ushort* __restrict__ hi,
                    ushort* __restrict__ lo)
{
    const int i = blockIdx.x * 256 + threadIdx.x;
    float4 v = ((const float4*)src)[i];
    ushort4 h, l;
    h.x = f2bf(v.x); l.x = f2bf(v.x - bf2f(h.x));
    h.y = f2bf(v.y); l.y = f2bf(v.y - bf2f(h.y));
    h.z = f2bf(v.z); l.z = f2bf(v.z - bf2f(h.z));
    h.w = f2bf(v.w); l.w = f2bf(v.w - bf2f(h.w));
    ((ushort4*)hi)[i] = h;
    ((ushort4*)lo)[i] = l;
}

// fp32 -> bf16 (activations)
__global__ __launch_bounds__(256)
void cvt_bf16_kernel(const float* __restrict__ src, ushort* __restrict__ dst)
{
    const int i = blockIdx.x * 256 + threadIdx.x;
    float4 v = ((const float4*)src)[i];
    ushort4 h;
    h.x = f2bf(v.x); h.y = f2bf(v.y); h.z = f2bf(v.z); h.w = f2bf(v.w);
    ((ushort4*)dst)[i] = h;
}

// C[M,N] = A[M,K](bf16) * (Bh+Bl)[N,K]^T (bf16 planes), fp32 accumulate.
// 128x128 tile, 4 waves, each wave 64x64 via 4x4 grid of 16x16x32 MFMA,
// 2 MFMA per fragment pair (hi, lo). Register-prefetched staging.
// EPI: 0 = fp32 store, 1 = softplus(v + bias[col]) fp32, 2 = bf16 store.
template <int EPI>
__global__ __launch_bounds__(256)
void gemm_mfma(const ushort* __restrict__ A, const ushort* __restrict__ Bh,
               const ushort* __restrict__ Bl, const float* __restrict__ bias,
               void* __restrict__ Cout, int N, int K)
{
    __shared__ ushort As[4096];    // [128 rows][32 k] bf16, 8 KB
    __shared__ ushort Bhs[4096];
    __shared__ ushort Bls[4096];

    const int tid  = threadIdx.x;
    const int lane = tid & 63;
    const int wave = tid >> 6;
    const int wm   = (wave >> 1) * 64;
    const int wn   = (wave & 1) * 64;
    const int row0 = blockIdx.y * 128;
    const int col0 = blockIdx.x * 128;

    // staging: chunk c (16 B = 8 bf16): row = c>>2, piece (c&3)*8.
    // thread t handles chunks t and t+256 (rows r, r+64).
    const int crow   = tid >> 2;
    const int cpiece = (tid & 3) * 8;
    const ushort* Ag0 = A  + (size_t)(row0 + crow) * K + cpiece;
    const ushort* Ag1 = A  + (size_t)(row0 + crow + 64) * K + cpiece;
    const ushort* Bg0 = Bh + (size_t)(col0 + crow) * K + cpiece;
    const ushort* Bg1 = Bh + (size_t)(col0 + crow + 64) * K + cpiece;
    const ushort* Cg0 = Bl + (size_t)(col0 + crow) * K + cpiece;
    const ushort* Cg1 = Bl + (size_t)(col0 + crow + 64) * K + cpiece;
    const int lds_off = tid * 8;   // ushort offset, chunk tid (linear)

    // fragment read offsets (ushort units): row*32 + quad*8
    const int fq  = (lane >> 4) * 8;
    const int fra = (wm + (lane & 15)) * 32 + fq;
    const int frb = (wn + (lane & 15)) * 32 + fq;

    f32x4 acc[4][4];
#pragma unroll
    for (int mi = 0; mi < 4; ++mi)
#pragma unroll
        for (int ni = 0; ni < 4; ++ni)
            acc[mi][ni] = (f32x4){0.f, 0.f, 0.f, 0.f};

    uint4 ra0 = *(const uint4*)Ag0, ra1 = *(const uint4*)Ag1;
    uint4 rh0 = *(const uint4*)Bg0, rh1 = *(const uint4*)Bg1;
    uint4 rl0 = *(const uint4*)Cg0, rl1 = *(const uint4*)Cg1;

    for (int k0 = 0; k0 < K; k0 += 32) {
        __syncthreads();                       // prev iter's ds_reads done
        *(uint4*)(As  + lds_off)        = ra0;
        *(uint4*)(As  + lds_off + 2048) = ra1;
        *(uint4*)(Bhs + lds_off)        = rh0;
        *(uint4*)(Bhs + lds_off + 2048) = rh1;
        *(uint4*)(Bls + lds_off)        = rl0;
        *(uint4*)(Bls + lds_off + 2048) = rl1;
        __syncthreads();
        if (k0 + 32 < K) {                     // prefetch next tile -> regs
            ra0 = *(const uint4*)(Ag0 + k0 + 32);
            ra1 = *(const uint4*)(Ag1 + k0 + 32);
            rh0 = *(const uint4*)(Bg0 + k0 + 32);
            rh1 = *(const uint4*)(Bg1 + k0 + 32);
            rl0 = *(const uint4*)(Cg0 + k0 + 32);
            rl1 = *(const uint4*)(Cg1 + k0 + 32);
        }
        bf16x8 af[4], bh[4], bl[4];
#pragma unroll
        for (int mi = 0; mi < 4; ++mi)
            af[mi] = *(const bf16x8*)(As + fra + mi * 512);
#pragma unroll
        for (int ni = 0; ni < 4; ++ni) {
            bh[ni] = *(const bf16x8*)(Bhs + frb + ni * 512);
            bl[ni] = *(const bf16x8*)(Bls + frb + ni * 512);
        }
#pragma unroll
        for (int mi = 0; mi < 4; ++mi)
#pragma unroll
            for (int ni = 0; ni < 4; ++ni) {
                acc[mi][ni] = __builtin_amdgcn_mfma_f32_16x16x32_bf16(
                    af[mi], bh[ni], acc[mi][ni], 0, 0, 0);
                acc[mi][ni] = __builtin_amdgcn_mfma_f32_16x16x32_bf16(
                    af[mi], bl[ni], acc[mi][ni], 0, 0, 0);
            }
    }

    // epilogue: C/D layout col=lane&15, row=(lane>>4)*4+reg  [m89-verified]
#pragma unroll
    for (int mi = 0; mi < 4; ++mi) {
        const int rg = row0 + wm + mi * 16 + (lane >> 4) * 4;
#pragma unroll
        for (int ni = 0; ni < 4; ++ni) {
            const int cg = col0 + wn + ni * 16 + (lane & 15);
            f32x4 v = acc[mi][ni];
            if (EPI == 1) {
                const float bv = bias[cg];
#pragma unroll
                for (int r = 0; r < 4; ++r) v[r] = softplus_f(v[r] + bv);
            }
#pragma unroll
            for (int r = 0; r < 4; ++r) {
                if (EPI == 2)
                    ((ushort*)Cout)[(size_t)(rg + r) * N + cg] = f2bf(v[r]);
                else
                    ((float*)Cout)[(size_t)(rg + r) * N + cg] = v[r];
            }
        }
    }
}

// Depthwise causal conv1d (4 taps) + bias + silu; bf16 in, bf16 out.
__global__ __launch_bounds__(256)
void conv_silu_kernel(const ushort* __restrict__ xi, const float* __restrict__ cw,
                      const float* __restrict__ cb, ushort* __restrict__ xc)
{
    const int idx = blockIdx.x * 256 + threadIdx.x;   // 8192*512 threads
    const int e   = (idx & 511) << 2;                 // channel, step 4
    const int row = idx >> 9;                         // b*L + l
    const int l   = row & 2047;

    const float4 w0 = *(const float4*)(cw + (size_t)(e + 0) * 4);
    const float4 w1 = *(const float4*)(cw + (size_t)(e + 1) * 4);
    const float4 w2 = *(const float4*)(cw + (size_t)(e + 2) * 4);
    const float4 w3 = *(const float4*)(cw + (size_t)(e + 3) * 4);

    float4 acc = *(const float4*)(cb + e);

#define CONV_TAP(K_, WSEL)                                                  \
    {                                                                       \
        ushort4 t = *(const ushort4*)(xi + (size_t)(row - (K_)) * 2048 + e);\
        acc.x = fmaf(bf2f(t.x), w0.WSEL, acc.x);                            \
        acc.y = fmaf(bf2f(t.y), w1.WSEL, acc.y);                            \
        acc.z = fmaf(bf2f(t.z), w2.WSEL, acc.z);                            \
        acc.w = fmaf(bf2f(t.w), w3.WSEL, acc.w);                            \
    }
    if (l >= 3) CONV_TAP(3, x)
    if (l >= 2) CONV_TAP(2, y)
    if (l >= 1) CONV_TAP(1, z)
    CONV_TAP(0, w)
#undef CONV_TAP

    ushort4 o;
    o.x = f2bf(silu_f(acc.x)); o.y = f2bf(silu_f(acc.y));
    o.z = f2bf(silu_f(acc.z)); o.w = f2bf(silu_f(acc.w));
    *(ushort4*)(xc + (size_t)row * 2048 + e) = o;
}

// bc = xc @ x_proj_w^T  (M=8192, N=32, K=2048). A is bf16, B fp32, guarded.
__global__ __launch_bounds__(256)
void gemm_bc_kernel(const ushort* __restrict__ A, const float* __restrict__ Bm,
                    float* __restrict__ C)
{
    const int NN = 32, K = 2048;
    __shared__ float As[8][128 + 4];
    __shared__ float Bs[8][128 + 4];

    const int tid  = threadIdx.x;
    const int row0 = blockIdx.y * 128;
    const int tm   = (tid >> 4) * 8;
    const int tn   = (tid & 15) * 8;
    const int lr   = tid >> 1;
    const int lk   = (tid & 1) * 4;

    const ushort* Ag = A + (size_t)(row0 + lr) * K + lk;
    const bool bok  = lr < NN;
    const float* Bg = Bm + (size_t)(bok ? lr : 0) * K + lk;

    float acc[8][8];
#pragma unroll
    for (int i = 0; i < 8; ++i)
#pragma unroll
        for (int j = 0; j < 8; ++j) acc[i][j] = 0.f;

    for (int k0 = 0; k0 < K; k0 += 8) {
        uint2 u = *(const uint2*)(Ag + k0);
        float4 av;
        av.x = __uint_as_float(u.x << 16);
        av.y = __uint_as_float(u.x & 0xFFFF0000u);
        av.z = __uint_as_float(u.y << 16);
        av.w = __uint_as_float(u.y & 0xFFFF0000u);
        float4 bv = bok ? *(const float4*)(Bg + k0) : make_float4(0.f, 0.f, 0.f, 0.f);
        __syncthreads();
        As[lk + 0][lr] = av.x; As[lk + 1][lr] = av.y;
        As[lk + 2][lr] = av.z; As[lk + 3][lr] = av.w;
        Bs[lk + 0][lr] = bv.x; Bs[lk + 1][lr] = bv.y;
        Bs[lk + 2][lr] = bv.z; Bs[lk + 3][lr] = bv.w;
        __syncthreads();
#pragma unroll
        for (int kk = 0; kk < 8; ++kk) {
            float a[8], b[8];
            *(float4*)&a[0] = *(const float4*)&As[kk][tm];
            *(float4*)&a[4] = *(const float4*)&As[kk][tm + 4];
            *(float4*)&b[0] = *(const float4*)&Bs[kk][tn];
            *(float4*)&b[4] = *(const float4*)&Bs[kk][tn + 4];
#pragma unroll
            for (int i = 0; i < 8; ++i)
#pragma unroll
                for (int j = 0; j < 8; ++j)
                    acc[i][j] = fmaf(a[i], b[j], acc[i][j]);
        }
    }

#pragma unroll
    for (int i = 0; i < 8; ++i) {
        float* Crow = C + (size_t)(row0 + tm + i) * NN;
#pragma unroll
        for (int j = 0; j < 8; ++j) {
            const int col = tn + j;
            if (col < NN) Crow[col] = acc[i][j];
        }
    }
}

// Selective scan. One lane per (b,d,s); 16-lane shfl_xor reduce. Blocked
// time loop (SCH) with double-buffered register prefetch of all 5 streams.
// Reads: delta fp32, xc bf16, z bf16, bc fp32. Writes: y bf16 (own buffer).
#define SCH 16

__global__ __launch_bounds__(256)
void scan_kernel(const ushort* __restrict__ zbuf, const ushort* __restrict__ xcb,
                 const float* __restrict__ dbuf, const float* __restrict__ bcbuf,
                 const float* __restrict__ A_log, const float* __restrict__ Dp,
                 ushort* __restrict__ ybuf)
{
    const int gid = blockIdx.x * 256 + threadIdx.x;  // 131072 lanes
    const int s   = gid & 15;
    const int ch  = gid >> 4;
    const int d   = ch & 2047;
    const int b   = ch >> 11;

    const float Aval = -__expf(A_log[(d << 4) + s]);
    const float Dv   = Dp[d];

    const size_t rbase = (size_t)b * 2048;
    const float*  dptr = dbuf  + rbase * 2048 + d;
    const ushort* xptr = xcb   + rbase * 2048 + d;
    const float*  bptr = bcbuf + rbase * 32 + s;
    const ushort* zptr = zbuf  + rbase * 2048 + d;
    ushort*       yptr = ybuf  + rbase * 2048 + d;

    float cdt[SCH], cxv[SCH], cBv[SCH], cCv[SCH], czv[SCH];
#pragma unroll
    for (int j = 0; j < SCH; ++j) {
        const size_t o = (size_t)j;
        cdt[j] = dptr[o * 2048];
        cxv[j] = bf2f(xptr[o * 2048]);
        cBv[j] = bptr[o * 32];
        cCv[j] = bptr[o * 32 + 16];
        czv[j] = bf2f(zptr[o * 2048]);
    }

    float h = 0.f;
    for (int l0 = 0; l0 < 2048; l0 += SCH) {
        float ndt[SCH], nxv[SCH], nBv[SCH], nCv[SCH], nzv[SCH];
        const bool more = (l0 + SCH) < 2048;
        if (more) {
#pragma unroll
            for (int j = 0; j < SCH; ++j) {
                const size_t o = (size_t)(l0 + SCH + j);
                ndt[j] = dptr[o * 2048];
                nxv[j] = bf2f(xptr[o * 2048]);
                nBv[j] = bptr[o * 32];
                nCv[j] = bptr[o * 32 + 16];
                nzv[j] = bf2f(zptr[o * 2048]);
            }
        }
#pragma unroll
        for (int j = 0; j < SCH; ++j) {
            h = __expf(cdt[j] * Aval) * h + (cdt[j] * cBv[j]) * cxv[j];
            float p = h * cCv[j];
            p += __shfl_xor(p, 1, 16);
            p += __shfl_xor(p, 2, 16);
            p += __shfl_xor(p, 4, 16);
            p += __shfl_xor(p, 8, 16);
            if (s == 0) {
                const float y = p + Dv * cxv[j];
                yptr[(size_t)(l0 + j) * 2048] = f2bf(y * silu_f(czv[j]));
            }
        }
        if (more) {
#pragma unroll
            for (int j = 0; j < SCH; ++j) {
                cdt[j] = ndt[j]; cxv[j] = nxv[j]; cBv[j] = nBv[j];
                cCv[j] = nCv[j]; czv[j] = nzv[j];
            }
        }
    }
}

extern "C" void kernel_launch(void* const* d_in, const int* in_sizes, int n_in,
                              void* d_out, int out_size, void* d_ws, size_t ws_size,
                              hipStream_t stream)
{
    const float* x          = (const float*)d_in[0];  // [4,2048,1024]
    const float* in_proj_w  = (const float*)d_in[1];  // [4096,1024]
    const float* conv_w     = (const float*)d_in[2];  // [2048,1,4]
    const float* conv_b     = (const float*)d_in[3];  // [2048]
    const float* x_proj_w   = (const float*)d_in[4];  // [32,2048]
    const float* dt_proj_w  = (const float*)d_in[5];  // [2048,2048]
    const float* dt_proj_b  = (const float*)d_in[6];  // [2048]
    const float* A_log      = (const float*)d_in[7];  // [2048,16]
    const float* Dp         = (const float*)d_in[8];  // [2048]
    const float* out_proj_w = (const float*)d_in[9];  // [1024,2048]
    float* out = (float*)d_out;                       // [4,2048,1024]

    // Workspace layout (201 MB)
    ushort* XI    = (ushort*)d_ws;                    // 32 MB; later Y'
    ushort* Z     = XI + 16777216;                    // 32 MB
    ushort* XC2   = Z + 16777216;                     // 32 MB
    float*  DELTA = (float*)(XC2 + 16777216);         // 64 MB
    ushort* XP    = (ushort*)DELTA;                   // x' bf16 (dead before DELTA written)
    ushort* WINH  = (ushort*)(DELTA + 16777216);      // [4096,1024] 8 MB
    ushort* WINL  = WINH + 4194304;                   // 8 MB
    ushort* WDTH  = WINL + 4194304;                   // [2048,2048] 8 MB
    ushort* WDTL  = WDTH + 4194304;                   // 8 MB
    ushort* WOUTH = WDTL + 4194304;                   // [1024,2048] 4 MB
    ushort* WOUTL = WOUTH + 2097152;                  // 4 MB
    float*  BC    = (float*)(WOUTL + 2097152);        // 1 MB
    ushort* Yp    = XI;                               // y bf16, reuses XI

    const dim3 blk(256);

    // 0) conversions
    cvt_bf16_kernel<<<dim3(8192), blk, 0, stream>>>(x, XP);
    split_w_kernel<<<dim3(4096), blk, 0, stream>>>(in_proj_w, WINH, WINL);
    split_w_kernel<<<dim3(4096), blk, 0, stream>>>(dt_proj_w, WDTH, WDTL);
    split_w_kernel<<<dim3(2048), blk, 0, stream>>>(out_proj_w, WOUTH, WOUTL);

    // 1) xi = x @ Win[0:2048]^T (bf16 out), z = x @ Win[2048:]^T (bf16 out)
    gemm_mfma<2><<<dim3(16, 64), blk, 0, stream>>>(XP, WINH, WINL, nullptr, XI, 2048, 1024);
    gemm_mfma<2><<<dim3(16, 64), blk, 0, stream>>>(XP, WINH + 2097152, WINL + 2097152,
                                                   nullptr, Z, 2048, 1024);

    // 2) xc = silu(conv(xi) + b) (bf16 out)
    conv_silu_kernel<<<dim3(16384), blk, 0, stream>>>(XI, conv_w, conv_b, XC2);

    // 3) delta = softplus(xc @ Wdt^T + b) (fp32 out; overwrites X' region)
    gemm_mfma<1><<<dim3(16, 64), blk, 0, stream>>>(XC2, WDTH, WDTL, dt_proj_b, DELTA, 2048, 2048);

    // 4) bc = xc @ x_proj_w^T (fp32)
    gemm_bc_kernel<<<dim3(1, 64), blk, 0, stream>>>(XC2, x_proj_w, BC);

    // 5) selective scan -> y bf16 (into XI buffer; xi dead after conv)
    scan_kernel<<<dim3(512), blk, 0, stream>>>(Z, XC2, DELTA, BC, A_log, Dp, Yp);

    // 6) out = y @ Wout^T (fp32 -> d_out)
    gemm_mfma<0><<<dim3(8, 64), blk, 0, stream>>>(Yp, WOUTH, WOUTL, nullptr, out, 1024, 2048);
}

// Round 5
// 1452.807 us; speedup vs baseline: 2.7012x; 1.0248x over previous
//
#include <hip/hip_runtime.h>
#include <hip/hip_bf16.h>

// MambaMinimalBlock: B=4, L=2048, D_MODEL=1024, D_STATE=16, D_CONV=4,
// D_INNER=2048, BL=8192. fp32 in/out.
//
// GEMMs: bf16 MFMA, weight-split (W = Whi + Wlo), bf16 activations.
// Scan: 2-pass chunked (NCHK=4 x 512 steps) — pass1 computes per-chunk
// boundary summaries (he, P=exp(A*sum dt)), pass2 runs all chunks in
// parallel from folded initial states. 4x the wave-parallelism of the
// monolithic scan, which was latency-bound on the serial shfl chain at
// 2 waves/SIMD (R4: 710 us, VALUBusy 47%, 4.2% HBM).
//
// Workspace (~206 MB of 256 MiB):
//   XI [8192,2048]bf16 32MB (-> Y') | Z 32MB | XC2 32MB | DELTA f32 64MB
//   (DELTA's first 16MB hosts X' bf16 pre-dt-GEMM) | W planes 40MB |
//   BC f32 1MB | SUMH 2.1MB | SUMP 2.1MB

typedef float  f32x4  __attribute__((ext_vector_type(4)));
typedef short  bf16x8 __attribute__((ext_vector_type(8)));

#define SCH  16
#define NCHK 4
#define CLEN 512

__device__ __forceinline__ ushort f2bf(float f) {
    uint u = __float_as_uint(f);
    u += 0x7FFF + ((u >> 16) & 1);          // RNE
    return (ushort)(u >> 16);
}
__device__ __forceinline__ float bf2f(ushort h) {
    return __uint_as_float((uint)h << 16);
}
__device__ __forceinline__ float softplus_f(float x) {
    return fmaxf(x, 0.f) + __logf(1.f + __expf(-fabsf(x)));
}
__device__ __forceinline__ float silu_f(float x) {
    return x / (1.f + __expf(-x));
}

__global__ __launch_bounds__(256)
void split_w_kernel(const float* __restrict__ src, ushort* __restrict__ hi,
                    ushort* __restrict__ lo)
{
    const int i = blockIdx.x * 256 + threadIdx.x;
    float4 v = ((const float4*)src)[i];
    ushort4 h, l;
    h.x = f2bf(v.x); l.x = f2bf(v.x - bf2f(h.x));
    h.y = f2bf(v.y); l.y = f2bf(v.y - bf2f(h.y));
    h.z = f2bf(v.z); l.z = f2bf(v.z - bf2f(h.z));
    h.w = f2bf(v.w); l.w = f2bf(v.w - bf2f(h.w));
    ((ushort4*)hi)[i] = h;
    ((ushort4*)lo)[i] = l;
}

__global__ __launch_bounds__(256)
void cvt_bf16_kernel(const float* __restrict__ src, ushort* __restrict__ dst)
{
    const int i = blockIdx.x * 256 + threadIdx.x;
    float4 v = ((const float4*)src)[i];
    ushort4 h;
    h.x = f2bf(v.x); h.y = f2bf(v.y); h.z = f2bf(v.z); h.w = f2bf(v.w);
    ((ushort4*)dst)[i] = h;
}

// C[M,N] = A[M,K](bf16) * (Bh+Bl)[N,K]^T (bf16 planes), fp32 accumulate.
// 128x128 tile, 4 waves x (4x4 of 16x16x32), 2 MFMA per fragment pair.
// EPI: 0 = fp32 store, 1 = softplus(v + bias[col]) fp32, 2 = bf16 store.
template <int EPI>
__global__ __launch_bounds__(256)
void gemm_mfma(const ushort* __restrict__ A, const ushort* __restrict__ Bh,
               const ushort* __restrict__ Bl, const float* __restrict__ bias,
               void* __restrict__ Cout, int N, int K)
{
    __shared__ ushort As[4096];
    __shared__ ushort Bhs[4096];
    __shared__ ushort Bls[4096];

    const int tid  = threadIdx.x;
    const int lane = tid & 63;
    const int wave = tid >> 6;
    const int wm   = (wave >> 1) * 64;
    const int wn   = (wave & 1) * 64;
    const int row0 = blockIdx.y * 128;
    const int col0 = blockIdx.x * 128;

    const int crow   = tid >> 2;
    const int cpiece = (tid & 3) * 8;
    const ushort* Ag0 = A  + (size_t)(row0 + crow) * K + cpiece;
    const ushort* Ag1 = A  + (size_t)(row0 + crow + 64) * K + cpiece;
    const ushort* Bg0 = Bh + (size_t)(col0 + crow) * K + cpiece;
    const ushort* Bg1 = Bh + (size_t)(col0 + crow + 64) * K + cpiece;
    const ushort* Cg0 = Bl + (size_t)(col0 + crow) * K + cpiece;
    const ushort* Cg1 = Bl + (size_t)(col0 + crow + 64) * K + cpiece;
    const int lds_off = tid * 8;

    const int fq  = (lane >> 4) * 8;
    const int fra = (wm + (lane & 15)) * 32 + fq;
    const int frb = (wn + (lane & 15)) * 32 + fq;

    f32x4 acc[4][4];
#pragma unroll
    for (int mi = 0; mi < 4; ++mi)
#pragma unroll
        for (int ni = 0; ni < 4; ++ni)
            acc[mi][ni] = (f32x4){0.f, 0.f, 0.f, 0.f};

    uint4 ra0 = *(const uint4*)Ag0, ra1 = *(const uint4*)Ag1;
    uint4 rh0 = *(const uint4*)Bg0, rh1 = *(const uint4*)Bg1;
    uint4 rl0 = *(const uint4*)Cg0, rl1 = *(const uint4*)Cg1;

    for (int k0 = 0; k0 < K; k0 += 32) {
        __syncthreads();
        *(uint4*)(As  + lds_off)        = ra0;
        *(uint4*)(As  + lds_off + 2048) = ra1;
        *(uint4*)(Bhs + lds_off)        = rh0;
        *(uint4*)(Bhs + lds_off + 2048) = rh1;
        *(uint4*)(Bls + lds_off)        = rl0;
        *(uint4*)(Bls + lds_off + 2048) = rl1;
        __syncthreads();
        if (k0 + 32 < K) {
            ra0 = *(const uint4*)(Ag0 + k0 + 32);
            ra1 = *(const uint4*)(Ag1 + k0 + 32);
            rh0 = *(const uint4*)(Bg0 + k0 + 32);
            rh1 = *(const uint4*)(Bg1 + k0 + 32);
            rl0 = *(const uint4*)(Cg0 + k0 + 32);
            rl1 = *(const uint4*)(Cg1 + k0 + 32);
        }
        bf16x8 af[4], bh[4], bl[4];
#pragma unroll
        for (int mi = 0; mi < 4; ++mi)
            af[mi] = *(const bf16x8*)(As + fra + mi * 512);
#pragma unroll
        for (int ni = 0; ni < 4; ++ni) {
            bh[ni] = *(const bf16x8*)(Bhs + frb + ni * 512);
            bl[ni] = *(const bf16x8*)(Bls + frb + ni * 512);
        }
#pragma unroll
        for (int mi = 0; mi < 4; ++mi)
#pragma unroll
            for (int ni = 0; ni < 4; ++ni) {
                acc[mi][ni] = __builtin_amdgcn_mfma_f32_16x16x32_bf16(
                    af[mi], bh[ni], acc[mi][ni], 0, 0, 0);
                acc[mi][ni] = __builtin_amdgcn_mfma_f32_16x16x32_bf16(
                    af[mi], bl[ni], acc[mi][ni], 0, 0, 0);
            }
    }

#pragma unroll
    for (int mi = 0; mi < 4; ++mi) {
        const int rg = row0 + wm + mi * 16 + (lane >> 4) * 4;
#pragma unroll
        for (int ni = 0; ni < 4; ++ni) {
            const int cg = col0 + wn + ni * 16 + (lane & 15);
            f32x4 v = acc[mi][ni];
            if (EPI == 1) {
                const float bv = bias[cg];
#pragma unroll
                for (int r = 0; r < 4; ++r) v[r] = softplus_f(v[r] + bv);
            }
#pragma unroll
            for (int r = 0; r < 4; ++r) {
                if (EPI == 2)
                    ((ushort*)Cout)[(size_t)(rg + r) * N + cg] = f2bf(v[r]);
                else
                    ((float*)Cout)[(size_t)(rg + r) * N + cg] = v[r];
            }
        }
    }
}

// Depthwise causal conv1d (4 taps) + bias + silu; bf16 in, bf16 out.
__global__ __launch_bounds__(256)
void conv_silu_kernel(const ushort* __restrict__ xi, const float* __restrict__ cw,
                      const float* __restrict__ cb, ushort* __restrict__ xc)
{
    const int idx = blockIdx.x * 256 + threadIdx.x;
    const int e   = (idx & 511) << 2;
    const int row = idx >> 9;
    const int l   = row & 2047;

    const float4 w0 = *(const float4*)(cw + (size_t)(e + 0) * 4);
    const float4 w1 = *(const float4*)(cw + (size_t)(e + 1) * 4);
    const float4 w2 = *(const float4*)(cw + (size_t)(e + 2) * 4);
    const float4 w3 = *(const float4*)(cw + (size_t)(e + 3) * 4);

    float4 acc = *(const float4*)(cb + e);

#define CONV_TAP(K_, WSEL)                                                  \
    {                                                                       \
        ushort4 t = *(const ushort4*)(xi + (size_t)(row - (K_)) * 2048 + e);\
        acc.x = fmaf(bf2f(t.x), w0.WSEL, acc.x);                            \
        acc.y = fmaf(bf2f(t.y), w1.WSEL, acc.y);                            \
        acc.z = fmaf(bf2f(t.z), w2.WSEL, acc.z);                            \
        acc.w = fmaf(bf2f(t.w), w3.WSEL, acc.w);                            \
    }
    if (l >= 3) CONV_TAP(3, x)
    if (l >= 2) CONV_TAP(2, y)
    if (l >= 1) CONV_TAP(1, z)
    CONV_TAP(0, w)
#undef CONV_TAP

    ushort4 o;
    o.x = f2bf(silu_f(acc.x)); o.y = f2bf(silu_f(acc.y));
    o.z = f2bf(silu_f(acc.z)); o.w = f2bf(silu_f(acc.w));
    *(ushort4*)(xc + (size_t)row * 2048 + e) = o;
}

// bc = xc @ x_proj_w^T  (M=8192, N=32, K=2048). A bf16, B fp32, guarded.
__global__ __launch_bounds__(256)
void gemm_bc_kernel(const ushort* __restrict__ A, const float* __restrict__ Bm,
                    float* __restrict__ C)
{
    const int NN = 32, K = 2048;
    __shared__ float As[8][128 + 4];
    __shared__ float Bs[8][128 + 4];

    const int tid  = threadIdx.x;
    const int row0 = blockIdx.y * 128;
    const int tm   = (tid >> 4) * 8;
    const int tn   = (tid & 15) * 8;
    const int lr   = tid >> 1;
    const int lk   = (tid & 1) * 4;

    const ushort* Ag = A + (size_t)(row0 + lr) * K + lk;
    const bool bok  = lr < NN;
    const float* Bg = Bm + (size_t)(bok ? lr : 0) * K + lk;

    float acc[8][8];
#pragma unroll
    for (int i = 0; i < 8; ++i)
#pragma unroll
        for (int j = 0; j < 8; ++j) acc[i][j] = 0.f;

    for (int k0 = 0; k0 < K; k0 += 8) {
        uint2 u = *(const uint2*)(Ag + k0);
        float4 av;
        av.x = __uint_as_float(u.x << 16);
        av.y = __uint_as_float(u.x & 0xFFFF0000u);
        av.z = __uint_as_float(u.y << 16);
        av.w = __uint_as_float(u.y & 0xFFFF0000u);
        float4 bv = bok ? *(const float4*)(Bg + k0) : make_float4(0.f, 0.f, 0.f, 0.f);
        __syncthreads();
        As[lk + 0][lr] = av.x; As[lk + 1][lr] = av.y;
        As[lk + 2][lr] = av.z; As[lk + 3][lr] = av.w;
        Bs[lk + 0][lr] = bv.x; Bs[lk + 1][lr] = bv.y;
        Bs[lk + 2][lr] = bv.z; Bs[lk + 3][lr] = bv.w;
        __syncthreads();
#pragma unroll
        for (int kk = 0; kk < 8; ++kk) {
            float a[8], b[8];
            *(float4*)&a[0] = *(const float4*)&As[kk][tm];
            *(float4*)&a[4] = *(const float4*)&As[kk][tm + 4];
            *(float4*)&b[0] = *(const float4*)&Bs[kk][tn];
            *(float4*)&b[4] = *(const float4*)&Bs[kk][tn + 4];
#pragma unroll
            for (int i = 0; i < 8; ++i)
#pragma unroll
                for (int j = 0; j < 8; ++j)
                    acc[i][j] = fmaf(a[i], b[j], acc[i][j]);
        }
    }

#pragma unroll
    for (int i = 0; i < 8; ++i) {
        float* Crow = C + (size_t)(row0 + tm + i) * NN;
#pragma unroll
        for (int j = 0; j < 8; ++j) {
            const int col = tn + j;
            if (col < NN) Crow[col] = acc[i][j];
        }
    }
}

// ---- Chunked selective scan ----
// Lane map (both passes): s = gid&15, d = (gid>>4)&2047, b = (gid>>15)&3,
// chunk c = gid>>17. Summary index: (((c*4+b)*2048+d)*16+s.

// Pass 1 (chunks 0..NCHK-2): h-recurrence from 0, no y; writes he and
// P = exp(A * sum dt) (== prod exp(dt*A), exact).
__global__ __launch_bounds__(256)
void scan_part1(const ushort* __restrict__ xcb, const float* __restrict__ dbuf,
                const float* __restrict__ bcbuf, const float* __restrict__ A_log,
                float* __restrict__ sum_h, float* __restrict__ sum_p)
{
    const int gid = blockIdx.x * 256 + threadIdx.x;  // 393216 lanes
    const int s   = gid & 15;
    const int ch  = (gid >> 4) & 8191;
    const int d   = ch & 2047;
    const int b   = ch >> 11;
    const int c   = gid >> 17;                       // 0..2

    const float Aval = -__expf(A_log[(d << 4) + s]);

    const size_t rbase = (size_t)b * 2048 + (size_t)c * CLEN;
    const float*  dptr = dbuf  + rbase * 2048 + d;
    const ushort* xptr = xcb   + rbase * 2048 + d;
    const float*  bptr = bcbuf + rbase * 32 + s;

    float cdt[SCH], cxv[SCH], cBv[SCH];
#pragma unroll
    for (int j = 0; j < SCH; ++j) {
        cdt[j] = dptr[(size_t)j * 2048];
        cxv[j] = bf2f(xptr[(size_t)j * 2048]);
        cBv[j] = bptr[(size_t)j * 32];
    }

    float h = 0.f, S = 0.f;
    for (int l0 = 0; l0 < CLEN; l0 += SCH) {
        float ndt[SCH], nxv[SCH], nBv[SCH];
        const bool more = (l0 + SCH) < CLEN;
        if (more) {
#pragma unroll
            for (int j = 0; j < SCH; ++j) {
                const size_t o = (size_t)(l0 + SCH + j);
                ndt[j] = dptr[o * 2048];
                nxv[j] = bf2f(xptr[o * 2048]);
                nBv[j] = bptr[o * 32];
            }
        }
#pragma unroll
        for (int j = 0; j < SCH; ++j) {
            h = __expf(cdt[j] * Aval) * h + (cdt[j] * cBv[j]) * cxv[j];
            S += cdt[j];
        }
        if (more) {
#pragma unroll
            for (int j = 0; j < SCH; ++j) {
                cdt[j] = ndt[j]; cxv[j] = nxv[j]; cBv[j] = nBv[j];
            }
        }
    }

    const size_t idx = (((size_t)c * 4 + b) * 2048 + d) * 16 + s;
    sum_h[idx] = h;
    sum_p[idx] = __expf(Aval * S);
}

// Pass 2 (all NCHK chunks in parallel): fold preceding summaries into
// h_init, then full scan with y = (C.h + D*x) * silu(z), bf16 out.
__global__ __launch_bounds__(256)
void scan_part2(const ushort* __restrict__ zbuf, const ushort* __restrict__ xcb,
                const float* __restrict__ dbuf, const float* __restrict__ bcbuf,
                const float* __restrict__ A_log, const float* __restrict__ Dp,
                const float* __restrict__ sum_h, const float* __restrict__ sum_p,
                ushort* __restrict__ ybuf)
{
    const int gid = blockIdx.x * 256 + threadIdx.x;  // 524288 lanes
    const int s   = gid & 15;
    const int ch  = (gid >> 4) & 8191;
    const int d   = ch & 2047;
    const int b   = ch >> 11;
    const int c   = gid >> 17;                       // 0..3 (block-uniform)

    const float Aval = -__expf(A_log[(d << 4) + s]);
    const float Dv   = Dp[d];

    float h = 0.f;
    for (int j = 0; j < c; ++j) {                    // fold chunk summaries
        const size_t idx = (((size_t)j * 4 + b) * 2048 + d) * 16 + s;
        h = sum_h[idx] + sum_p[idx] * h;
    }

    const size_t rbase = (size_t)b * 2048 + (size_t)c * CLEN;
    const float*  dptr = dbuf  + rbase * 2048 + d;
    const ushort* xptr = xcb   + rbase * 2048 + d;
    const float*  bptr = bcbuf + rbase * 32 + s;
    const ushort* zptr = zbuf  + rbase * 2048 + d;
    ushort*       yptr = ybuf  + rbase * 2048 + d;

    float cdt[SCH], cxv[SCH], cBv[SCH], cCv[SCH], czv[SCH];
#pragma unroll
    for (int j = 0; j < SCH; ++j) {
        cdt[j] = dptr[(size_t)j * 2048];
        cxv[j] = bf2f(xptr[(size_t)j * 2048]);
        cBv[j] = bptr[(size_t)j * 32];
        cCv[j] = bptr[(size_t)j * 32 + 16];
        czv[j] = bf2f(zptr[(size_t)j * 2048]);
    }

    for (int l0 = 0; l0 < CLEN; l0 += SCH) {
        float ndt[SCH], nxv[SCH], nBv[SCH], nCv[SCH], nzv[SCH];
        const bool more = (l0 + SCH) < CLEN;
        if (more) {
#pragma unroll
            for (int j = 0; j < SCH; ++j) {
                const size_t o = (size_t)(l0 + SCH + j);
                ndt[j] = dptr[o * 2048];
                nxv[j] = bf2f(xptr[o * 2048]);
                nBv[j] = bptr[o * 32];
                nCv[j] = bptr[o * 32 + 16];
                nzv[j] = bf2f(zptr[o * 2048]);
            }
        }
#pragma unroll
        for (int j = 0; j < SCH; ++j) {
            h = __expf(cdt[j] * Aval) * h + (cdt[j] * cBv[j]) * cxv[j];
            float p = h * cCv[j];
            p += __shfl_xor(p, 1, 16);
            p += __shfl_xor(p, 2, 16);
            p += __shfl_xor(p, 4, 16);
            p += __shfl_xor(p, 8, 16);
            if (s == 0) {
                const float y = p + Dv * cxv[j];
                yptr[(size_t)(l0 + j) * 2048] = f2bf(y * silu_f(czv[j]));
            }
        }
        if (more) {
#pragma unroll
            for (int j = 0; j < SCH; ++j) {
                cdt[j] = ndt[j]; cxv[j] = nxv[j]; cBv[j] = nBv[j];
                cCv[j] = nCv[j]; czv[j] = nzv[j];
            }
        }
    }
}

extern "C" void kernel_launch(void* const* d_in, const int* in_sizes, int n_in,
                              void* d_out, int out_size, void* d_ws, size_t ws_size,
                              hipStream_t stream)
{
    const float* x          = (const float*)d_in[0];
    const float* in_proj_w  = (const float*)d_in[1];
    const float* conv_w     = (const float*)d_in[2];
    const float* conv_b     = (const float*)d_in[3];
    const float* x_proj_w   = (const float*)d_in[4];
    const float* dt_proj_w  = (const float*)d_in[5];
    const float* dt_proj_b  = (const float*)d_in[6];
    const float* A_log      = (const float*)d_in[7];
    const float* Dp         = (const float*)d_in[8];
    const float* out_proj_w = (const float*)d_in[9];
    float* out = (float*)d_out;

    ushort* XI    = (ushort*)d_ws;                    // 32 MB; later Y'
    ushort* Z     = XI + 16777216;                    // 32 MB
    ushort* XC2   = Z + 16777216;                     // 32 MB
    float*  DELTA = (float*)(XC2 + 16777216);         // 64 MB
    ushort* XP    = (ushort*)DELTA;                   // x' bf16 (pre-DELTA)
    ushort* WINH  = (ushort*)(DELTA + 16777216);      // 8 MB
    ushort* WINL  = WINH + 4194304;                   // 8 MB
    ushort* WDTH  = WINL + 4194304;                   // 8 MB
    ushort* WDTL  = WDTH + 4194304;                   // 8 MB
    ushort* WOUTH = WDTL + 4194304;                   // 4 MB
    ushort* WOUTL = WOUTH + 2097152;                  // 4 MB
    float*  BC    = (float*)(WOUTL + 2097152);        // 1 MB
    float*  SUMH  = BC + 262144;                      // 2.1 MB (4 chunks cap)
    float*  SUMP  = SUMH + 524288;                    // 2.1 MB
    ushort* Yp    = XI;

    const dim3 blk(256);

    // 0) conversions
    cvt_bf16_kernel<<<dim3(8192), blk, 0, stream>>>(x, XP);
    split_w_kernel<<<dim3(4096), blk, 0, stream>>>(in_proj_w, WINH, WINL);
    split_w_kernel<<<dim3(4096), blk, 0, stream>>>(dt_proj_w, WDTH, WDTL);
    split_w_kernel<<<dim3(2048), blk, 0, stream>>>(out_proj_w, WOUTH, WOUTL);

    // 1) xi, z
    gemm_mfma<2><<<dim3(16, 64), blk, 0, stream>>>(XP, WINH, WINL, nullptr, XI, 2048, 1024);
    gemm_mfma<2><<<dim3(16, 64), blk, 0, stream>>>(XP, WINH + 2097152, WINL + 2097152,
                                                   nullptr, Z, 2048, 1024);

    // 2) xc = silu(conv(xi) + b)
    conv_silu_kernel<<<dim3(16384), blk, 0, stream>>>(XI, conv_w, conv_b, XC2);

    // 3) delta = softplus(xc @ Wdt^T + b)
    gemm_mfma<1><<<dim3(16, 64), blk, 0, stream>>>(XC2, WDTH, WDTL, dt_proj_b, DELTA, 2048, 2048);

    // 4) bc = xc @ x_proj_w^T
    gemm_bc_kernel<<<dim3(1, 64), blk, 0, stream>>>(XC2, x_proj_w, BC);

    // 5) chunked scan: pass1 (chunks 0..2) then pass2 (all 4)
    scan_part1<<<dim3(1536), blk, 0, stream>>>(XC2, DELTA, BC, A_log, SUMH, SUMP);
    scan_part2<<<dim3(2048), blk, 0, stream>>>(Z, XC2, DELTA, BC, A_log, Dp,
                                               SUMH, SUMP, Yp);

    // 6) out = y @ Wout^T
    gemm_mfma<0><<<dim3(8, 64), blk, 0, stream>>>(Yp, WOUTH, WOUTL, nullptr, out, 1024, 2048);
}

// Round 6
// 991.148 us; speedup vs baseline: 3.9593x; 1.4658x over previous
//
#include <hip/hip_runtime.h>
#include <hip/hip_bf16.h>

// MambaMinimalBlock: B=4, L=2048, D_MODEL=1024, D_STATE=16, D_CONV=4,
// D_INNER=2048, BL=8192. fp32 in/out.
//
// GEMMs: bf16 MFMA, weight-split (W = Whi + Wlo), bf16 activations.
// Scan v3 (R6): d-parallel layout — one lane per channel d, h[16] in VGPRs.
//   * no cross-lane reduce (y-dot in registers)
//   * all channel streams coalesced (64 consecutive d per wave)
//   * B/C wave-uniform broadcast loads, prefetched 1 step ahead
//   * NCHK=16 chunks of CLEN=128 (2-pass chunked recurrence) for wave count
// R5's (b,d,s)-per-lane scan was latency-bound on address-divergent scalar
// loads (598 us, 5% HBM, VALUBusy 56%); this layout removes that cause.
//
// Workspace (~217 MB of 256 MiB):
//   XI/Z/XC2 bf16 32MB each | DELTA f32 64MB (first 16MB hosts X' bf16)
//   W planes 40MB | BC f32 1MB | SUMH/SUMP f32 8MB each

typedef float  f32x4  __attribute__((ext_vector_type(4)));
typedef short  bf16x8 __attribute__((ext_vector_type(8)));

#define NCHK 16
#define CLEN 128
#define SW   8      // scan window (double-buffered)

__device__ __forceinline__ ushort f2bf(float f) {
    uint u = __float_as_uint(f);
    u += 0x7FFF + ((u >> 16) & 1);          // RNE
    return (ushort)(u >> 16);
}
__device__ __forceinline__ float bf2f(ushort h) {
    return __uint_as_float((uint)h << 16);
}
__device__ __forceinline__ float softplus_f(float x) {
    return fmaxf(x, 0.f) + __logf(1.f + __expf(-fabsf(x)));
}
__device__ __forceinline__ float silu_f(float x) {
    return x / (1.f + __expf(-x));
}

__global__ __launch_bounds__(256)
void split_w_kernel(const float* __restrict__ src, ushort* __restrict__ hi,
                    ushort* __restrict__ lo)
{
    const int i = blockIdx.x * 256 + threadIdx.x;
    float4 v = ((const float4*)src)[i];
    ushort4 h, l;
    h.x = f2bf(v.x); l.x = f2bf(v.x - bf2f(h.x));
    h.y = f2bf(v.y); l.y = f2bf(v.y - bf2f(h.y));
    h.z = f2bf(v.z); l.z = f2bf(v.z - bf2f(h.z));
    h.w = f2bf(v.w); l.w = f2bf(v.w - bf2f(h.w));
    ((ushort4*)hi)[i] = h;
    ((ushort4*)lo)[i] = l;
}

__global__ __launch_bounds__(256)
void cvt_bf16_kernel(const float* __restrict__ src, ushort* __restrict__ dst)
{
    const int i = blockIdx.x * 256 + threadIdx.x;
    float4 v = ((const float4*)src)[i];
    ushort4 h;
    h.x = f2bf(v.x); h.y = f2bf(v.y); h.z = f2bf(v.z); h.w = f2bf(v.w);
    ((ushort4*)dst)[i] = h;
}

// C[M,N] = A[M,K](bf16) * (Bh+Bl)[N,K]^T (bf16 planes), fp32 accumulate.
// EPI: 0 = fp32 store, 1 = softplus(v + bias[col]) fp32, 2 = bf16 store.
template <int EPI>
__global__ __launch_bounds__(256)
void gemm_mfma(const ushort* __restrict__ A, const ushort* __restrict__ Bh,
               const ushort* __restrict__ Bl, const float* __restrict__ bias,
               void* __restrict__ Cout, int N, int K)
{
    __shared__ ushort As[4096];
    __shared__ ushort Bhs[4096];
    __shared__ ushort Bls[4096];

    const int tid  = threadIdx.x;
    const int lane = tid & 63;
    const int wave = tid >> 6;
    const int wm   = (wave >> 1) * 64;
    const int wn   = (wave & 1) * 64;
    const int row0 = blockIdx.y * 128;
    const int col0 = blockIdx.x * 128;

    const int crow   = tid >> 2;
    const int cpiece = (tid & 3) * 8;
    const ushort* Ag0 = A  + (size_t)(row0 + crow) * K + cpiece;
    const ushort* Ag1 = A  + (size_t)(row0 + crow + 64) * K + cpiece;
    const ushort* Bg0 = Bh + (size_t)(col0 + crow) * K + cpiece;
    const ushort* Bg1 = Bh + (size_t)(col0 + crow + 64) * K + cpiece;
    const ushort* Cg0 = Bl + (size_t)(col0 + crow) * K + cpiece;
    const ushort* Cg1 = Bl + (size_t)(col0 + crow + 64) * K + cpiece;
    const int lds_off = tid * 8;

    const int fq  = (lane >> 4) * 8;
    const int fra = (wm + (lane & 15)) * 32 + fq;
    const int frb = (wn + (lane & 15)) * 32 + fq;

    f32x4 acc[4][4];
#pragma unroll
    for (int mi = 0; mi < 4; ++mi)
#pragma unroll
        for (int ni = 0; ni < 4; ++ni)
            acc[mi][ni] = (f32x4){0.f, 0.f, 0.f, 0.f};

    uint4 ra0 = *(const uint4*)Ag0, ra1 = *(const uint4*)Ag1;
    uint4 rh0 = *(const uint4*)Bg0, rh1 = *(const uint4*)Bg1;
    uint4 rl0 = *(const uint4*)Cg0, rl1 = *(const uint4*)Cg1;

    for (int k0 = 0; k0 < K; k0 += 32) {
        __syncthreads();
        *(uint4*)(As  + lds_off)        = ra0;
        *(uint4*)(As  + lds_off + 2048) = ra1;
        *(uint4*)(Bhs + lds_off)        = rh0;
        *(uint4*)(Bhs + lds_off + 2048) = rh1;
        *(uint4*)(Bls + lds_off)        = rl0;
        *(uint4*)(Bls + lds_off + 2048) = rl1;
        __syncthreads();
        if (k0 + 32 < K) {
            ra0 = *(const uint4*)(Ag0 + k0 + 32);
            ra1 = *(const uint4*)(Ag1 + k0 + 32);
            rh0 = *(const uint4*)(Bg0 + k0 + 32);
            rh1 = *(const uint4*)(Bg1 + k0 + 32);
            rl0 = *(const uint4*)(Cg0 + k0 + 32);
            rl1 = *(const uint4*)(Cg1 + k0 + 32);
        }
        bf16x8 af[4], bh[4], bl[4];
#pragma unroll
        for (int mi = 0; mi < 4; ++mi)
            af[mi] = *(const bf16x8*)(As + fra + mi * 512);
#pragma unroll
        for (int ni = 0; ni < 4; ++ni) {
            bh[ni] = *(const bf16x8*)(Bhs + frb + ni * 512);
            bl[ni] = *(const bf16x8*)(Bls + frb + ni * 512);
        }
#pragma unroll
        for (int mi = 0; mi < 4; ++mi)
#pragma unroll
            for (int ni = 0; ni < 4; ++ni) {
                acc[mi][ni] = __builtin_amdgcn_mfma_f32_16x16x32_bf16(
                    af[mi], bh[ni], acc[mi][ni], 0, 0, 0);
                acc[mi][ni] = __builtin_amdgcn_mfma_f32_16x16x32_bf16(
                    af[mi], bl[ni], acc[mi][ni], 0, 0, 0);
            }
    }

#pragma unroll
    for (int mi = 0; mi < 4; ++mi) {
        const int rg = row0 + wm + mi * 16 + (lane >> 4) * 4;
#pragma unroll
        for (int ni = 0; ni < 4; ++ni) {
            const int cg = col0 + wn + ni * 16 + (lane & 15);
            f32x4 v = acc[mi][ni];
            if (EPI == 1) {
                const float bv = bias[cg];
#pragma unroll
                for (int r = 0; r < 4; ++r) v[r] = softplus_f(v[r] + bv);
            }
#pragma unroll
            for (int r = 0; r < 4; ++r) {
                if (EPI == 2)
                    ((ushort*)Cout)[(size_t)(rg + r) * N + cg] = f2bf(v[r]);
                else
                    ((float*)Cout)[(size_t)(rg + r) * N + cg] = v[r];
            }
        }
    }
}

// Depthwise causal conv1d (4 taps) + bias + silu; bf16 in, bf16 out.
__global__ __launch_bounds__(256)
void conv_silu_kernel(const ushort* __restrict__ xi, const float* __restrict__ cw,
                      const float* __restrict__ cb, ushort* __restrict__ xc)
{
    const int idx = blockIdx.x * 256 + threadIdx.x;
    const int e   = (idx & 511) << 2;
    const int row = idx >> 9;
    const int l   = row & 2047;

    const float4 w0 = *(const float4*)(cw + (size_t)(e + 0) * 4);
    const float4 w1 = *(const float4*)(cw + (size_t)(e + 1) * 4);
    const float4 w2 = *(const float4*)(cw + (size_t)(e + 2) * 4);
    const float4 w3 = *(const float4*)(cw + (size_t)(e + 3) * 4);

    float4 acc = *(const float4*)(cb + e);

#define CONV_TAP(K_, WSEL)                                                  \
    {                                                                       \
        ushort4 t = *(const ushort4*)(xi + (size_t)(row - (K_)) * 2048 + e);\
        acc.x = fmaf(bf2f(t.x), w0.WSEL, acc.x);                            \
        acc.y = fmaf(bf2f(t.y), w1.WSEL, acc.y);                            \
        acc.z = fmaf(bf2f(t.z), w2.WSEL, acc.z);                            \
        acc.w = fmaf(bf2f(t.w), w3.WSEL, acc.w);                            \
    }
    if (l >= 3) CONV_TAP(3, x)
    if (l >= 2) CONV_TAP(2, y)
    if (l >= 1) CONV_TAP(1, z)
    CONV_TAP(0, w)
#undef CONV_TAP

    ushort4 o;
    o.x = f2bf(silu_f(acc.x)); o.y = f2bf(silu_f(acc.y));
    o.z = f2bf(silu_f(acc.z)); o.w = f2bf(silu_f(acc.w));
    *(ushort4*)(xc + (size_t)row * 2048 + e) = o;
}

// bc = xc @ x_proj_w^T  (M=8192, N=32, K=2048). A bf16, B fp32, guarded.
__global__ __launch_bounds__(256)
void gemm_bc_kernel(const ushort* __restrict__ A, const float* __restrict__ Bm,
                    float* __restrict__ C)
{
    const int NN = 32, K = 2048;
    __shared__ float As[8][128 + 4];
    __shared__ float Bs[8][128 + 4];

    const int tid  = threadIdx.x;
    const int row0 = blockIdx.y * 128;
    const int tm   = (tid >> 4) * 8;
    const int tn   = (tid & 15) * 8;
    const int lr   = tid >> 1;
    const int lk   = (tid & 1) * 4;

    const ushort* Ag = A + (size_t)(row0 + lr) * K + lk;
    const bool bok  = lr < NN;
    const float* Bg = Bm + (size_t)(bok ? lr : 0) * K + lk;

    float acc[8][8];
#pragma unroll
    for (int i = 0; i < 8; ++i)
#pragma unroll
        for (int j = 0; j < 8; ++j) acc[i][j] = 0.f;

    for (int k0 = 0; k0 < K; k0 += 8) {
        uint2 u = *(const uint2*)(Ag + k0);
        float4 av;
        av.x = __uint_as_float(u.x << 16);
        av.y = __uint_as_float(u.x & 0xFFFF0000u);
        av.z = __uint_as_float(u.y << 16);
        av.w = __uint_as_float(u.y & 0xFFFF0000u);
        float4 bv = bok ? *(const float4*)(Bg + k0) : make_float4(0.f, 0.f, 0.f, 0.f);
        __syncthreads();
        As[lk + 0][lr] = av.x; As[lk + 1][lr] = av.y;
        As[lk + 2][lr] = av.z; As[lk + 3][lr] = av.w;
        Bs[lk + 0][lr] = bv.x; Bs[lk + 1][lr] = bv.y;
        Bs[lk + 2][lr] = bv.z; Bs[lk + 3][lr] = bv.w;
        __syncthreads();
#pragma unroll
        for (int kk = 0; kk < 8; ++kk) {
            float a[8], b[8];
            *(float4*)&a[0] = *(const float4*)&As[kk][tm];
            *(float4*)&a[4] = *(const float4*)&As[kk][tm + 4];
            *(float4*)&b[0] = *(const float4*)&Bs[kk][tn];
            *(float4*)&b[4] = *(const float4*)&Bs[kk][tn + 4];
#pragma unroll
            for (int i = 0; i < 8; ++i)
#pragma unroll
                for (int j = 0; j < 8; ++j)
                    acc[i][j] = fmaf(a[i], b[j], acc[i][j]);
        }
    }

#pragma unroll
    for (int i = 0; i < 8; ++i) {
        float* Crow = C + (size_t)(row0 + tm + i) * NN;
#pragma unroll
        for (int j = 0; j < 8; ++j) {
            const int col = tn + j;
            if (col < NN) Crow[col] = acc[i][j];
        }
    }
}

// ---- d-parallel chunked selective scan ----
// Block: 256 lanes = 256 consecutive d. blockIdx = c*32 + b*8 + dblk.
// Lane state: h[16] (fp32 VGPRs), Aval[16]. Summary index:
// (((c*4+b)*2048+d)*16 + s, lane-contiguous 16 floats.

// Pass 1: chunks 0..NCHK-2, h from 0, writes he + P = exp(A * sum dt).
__global__ __launch_bounds__(256)
void scan_part1(const ushort* __restrict__ xcb, const float* __restrict__ dbuf,
                const float* __restrict__ bcbuf, const float* __restrict__ A_log,
                float* __restrict__ sum_h, float* __restrict__ sum_p)
{
    const int c    = blockIdx.x >> 5;          // 0..14
    const int b    = (blockIdx.x >> 3) & 3;
    const int dblk = blockIdx.x & 7;
    const int d    = dblk * 256 + threadIdx.x;

    float Aval[16];
#pragma unroll
    for (int q = 0; q < 4; ++q) {
        float4 al = *(const float4*)(A_log + (size_t)d * 16 + q * 4);
        Aval[q*4+0] = -__expf(al.x); Aval[q*4+1] = -__expf(al.y);
        Aval[q*4+2] = -__expf(al.z); Aval[q*4+3] = -__expf(al.w);
    }

    const size_t row0 = (size_t)b * 2048 + (size_t)c * CLEN;
    const float*  dp  = dbuf + row0 * 2048 + d;
    const ushort* xp  = xcb  + row0 * 2048 + d;
    const float*  bcp = bcbuf + row0 * 32;

    float h[16];
#pragma unroll
    for (int s = 0; s < 16; ++s) h[s] = 0.f;
    float S = 0.f;

    float wdt[SW], wxv[SW];
#pragma unroll
    for (int j = 0; j < SW; ++j) {
        wdt[j] = dp[(size_t)j * 2048];
        wxv[j] = bf2f(xp[(size_t)j * 2048]);
    }
    float curB[16];
#pragma unroll
    for (int q = 0; q < 4; ++q)
        *(float4*)&curB[q*4] = *(const float4*)(bcp + q * 4);

    for (int l0 = 0; l0 < CLEN; l0 += SW) {
        float ndt[SW], nxv[SW];
        const bool more = (l0 + SW) < CLEN;
        if (more) {
#pragma unroll
            for (int j = 0; j < SW; ++j) {
                const size_t o = (size_t)(l0 + SW + j);
                ndt[j] = dp[o * 2048];
                nxv[j] = bf2f(xp[o * 2048]);
            }
        }
#pragma unroll
        for (int j = 0; j < SW; ++j) {
            const int l = l0 + j;
            float nB[16];
            if (l + 1 < CLEN) {
#pragma unroll
                for (int q = 0; q < 4; ++q)
                    *(float4*)&nB[q*4] = *(const float4*)(bcp + (size_t)(l+1) * 32 + q * 4);
            }
            const float dt = wdt[j];
            const float t  = dt * wxv[j];
            S += dt;
#pragma unroll
            for (int s = 0; s < 16; ++s)
                h[s] = __expf(dt * Aval[s]) * h[s] + curB[s] * t;
            if (l + 1 < CLEN) {
#pragma unroll
                for (int s = 0; s < 16; ++s) curB[s] = nB[s];
            }
        }
        if (more) {
#pragma unroll
            for (int j = 0; j < SW; ++j) { wdt[j] = ndt[j]; wxv[j] = nxv[j]; }
        }
    }

    float* sh = sum_h + ((((size_t)c * 4 + b) * 2048 + d) << 4);
    float* sp = sum_p + ((((size_t)c * 4 + b) * 2048 + d) << 4);
#pragma unroll
    for (int q = 0; q < 4; ++q) {
        *(float4*)(sh + q * 4) = make_float4(h[q*4], h[q*4+1], h[q*4+2], h[q*4+3]);
        *(float4*)(sp + q * 4) = make_float4(__expf(Aval[q*4] * S), __expf(Aval[q*4+1] * S),
                                             __expf(Aval[q*4+2] * S), __expf(Aval[q*4+3] * S));
    }
}

// Pass 2: all NCHK chunks; fold preceding summaries, scan, y bf16 out.
__global__ __launch_bounds__(256)
void scan_part2(const ushort* __restrict__ zbuf, const ushort* __restrict__ xcb,
                const float* __restrict__ dbuf, const float* __restrict__ bcbuf,
                const float* __restrict__ A_log, const float* __restrict__ Dp,
                const float* __restrict__ sum_h, const float* __restrict__ sum_p,
                ushort* __restrict__ ybuf)
{
    const int c    = blockIdx.x >> 5;          // 0..15
    const int b    = (blockIdx.x >> 3) & 3;
    const int dblk = blockIdx.x & 7;
    const int d    = dblk * 256 + threadIdx.x;

    float Aval[16];
#pragma unroll
    for (int q = 0; q < 4; ++q) {
        float4 al = *(const float4*)(A_log + (size_t)d * 16 + q * 4);
        Aval[q*4+0] = -__expf(al.x); Aval[q*4+1] = -__expf(al.y);
        Aval[q*4+2] = -__expf(al.z); Aval[q*4+3] = -__expf(al.w);
    }
    const float Dv = Dp[d];

    float h[16];
#pragma unroll
    for (int s = 0; s < 16; ++s) h[s] = 0.f;
    for (int j = 0; j < c; ++j) {              // fold chunk summaries
        const float* sh = sum_h + ((((size_t)j * 4 + b) * 2048 + d) << 4);
        const float* sp = sum_p + ((((size_t)j * 4 + b) * 2048 + d) << 4);
#pragma unroll
        for (int q = 0; q < 4; ++q) {
            float4 vh = *(const float4*)(sh + q * 4);
            float4 vp = *(const float4*)(sp + q * 4);
            h[q*4+0] = vh.x + vp.x * h[q*4+0];
            h[q*4+1] = vh.y + vp.y * h[q*4+1];
            h[q*4+2] = vh.z + vp.z * h[q*4+2];
            h[q*4+3] = vh.w + vp.w * h[q*4+3];
        }
    }

    const size_t row0 = (size_t)b * 2048 + (size_t)c * CLEN;
    const float*  dp  = dbuf + row0 * 2048 + d;
    const ushort* xp  = xcb  + row0 * 2048 + d;
    const ushort* zp  = zbuf + row0 * 2048 + d;
    const float*  bcp = bcbuf + row0 * 32;
    ushort*       yp  = ybuf + row0 * 2048 + d;

    float wdt[SW], wxv[SW], wzv[SW];
#pragma unroll
    for (int j = 0; j < SW; ++j) {
        wdt[j] = dp[(size_t)j * 2048];
        wxv[j] = bf2f(xp[(size_t)j * 2048]);
        wzv[j] = bf2f(zp[(size_t)j * 2048]);
    }
    float curB[16], curC[16];
#pragma unroll
    for (int q = 0; q < 4; ++q) {
        *(float4*)&curB[q*4] = *(const float4*)(bcp + q * 4);
        *(float4*)&curC[q*4] = *(const float4*)(bcp + 16 + q * 4);
    }

    for (int l0 = 0; l0 < CLEN; l0 += SW) {
        float ndt[SW], nxv[SW], nzv[SW];
        const bool more = (l0 + SW) < CLEN;
        if (more) {
#pragma unroll
            for (int j = 0; j < SW; ++j) {
                const size_t o = (size_t)(l0 + SW + j);
                ndt[j] = dp[o * 2048];
                nxv[j] = bf2f(xp[o * 2048]);
                nzv[j] = bf2f(zp[o * 2048]);
            }
        }
#pragma unroll
        for (int j = 0; j < SW; ++j) {
            const int l = l0 + j;
            float nB[16], nC[16];
            if (l + 1 < CLEN) {
#pragma unroll
                for (int q = 0; q < 4; ++q) {
                    *(float4*)&nB[q*4] = *(const float4*)(bcp + (size_t)(l+1) * 32 + q * 4);
                    *(float4*)&nC[q*4] = *(const float4*)(bcp + (size_t)(l+1) * 32 + 16 + q * 4);
                }
            }
            const float dt = wdt[j];
            const float t  = dt * wxv[j];
#pragma unroll
            for (int s = 0; s < 16; ++s)
                h[s] = __expf(dt * Aval[s]) * h[s] + curB[s] * t;
            float y0 = 0.f, y1 = 0.f, y2 = 0.f, y3 = 0.f;
#pragma unroll
            for (int s = 0; s < 16; s += 4) {
                y0 = fmaf(h[s+0], curC[s+0], y0);
                y1 = fmaf(h[s+1], curC[s+1], y1);
                y2 = fmaf(h[s+2], curC[s+2], y2);
                y3 = fmaf(h[s+3], curC[s+3], y3);
            }
            float y = (y0 + y1) + (y2 + y3) + Dv * wxv[j];
            yp[(size_t)l * 2048] = f2bf(y * silu_f(wzv[j]));
            if (l + 1 < CLEN) {
#pragma unroll
                for (int s = 0; s < 16; ++s) { curB[s] = nB[s]; curC[s] = nC[s]; }
            }
        }
        if (more) {
#pragma unroll
            for (int j = 0; j < SW; ++j) {
                wdt[j] = ndt[j]; wxv[j] = nxv[j]; wzv[j] = nzv[j];
            }
        }
    }
}

extern "C" void kernel_launch(void* const* d_in, const int* in_sizes, int n_in,
                              void* d_out, int out_size, void* d_ws, size_t ws_size,
                              hipStream_t stream)
{
    const float* x          = (const float*)d_in[0];
    const float* in_proj_w  = (const float*)d_in[1];
    const float* conv_w     = (const float*)d_in[2];
    const float* conv_b     = (const float*)d_in[3];
    const float* x_proj_w   = (const float*)d_in[4];
    const float* dt_proj_w  = (const float*)d_in[5];
    const float* dt_proj_b  = (const float*)d_in[6];
    const float* A_log      = (const float*)d_in[7];
    const float* Dp         = (const float*)d_in[8];
    const float* out_proj_w = (const float*)d_in[9];
    float* out = (float*)d_out;

    ushort* XI    = (ushort*)d_ws;                    // 32 MB; later Y'
    ushort* Z     = XI + 16777216;                    // 32 MB
    ushort* XC2   = Z + 16777216;                     // 32 MB
    float*  DELTA = (float*)(XC2 + 16777216);         // 64 MB
    ushort* XP    = (ushort*)DELTA;                   // x' bf16 (pre-DELTA)
    ushort* WINH  = (ushort*)(DELTA + 16777216);      // 8 MB
    ushort* WINL  = WINH + 4194304;                   // 8 MB
    ushort* WDTH  = WINL + 4194304;                   // 8 MB
    ushort* WDTL  = WDTH + 4194304;                   // 8 MB
    ushort* WOUTH = WDTL + 4194304;                   // 4 MB
    ushort* WOUTL = WOUTH + 2097152;                  // 4 MB
    float*  BC    = (float*)(WOUTL + 2097152);        // 1 MB
    float*  SUMH  = BC + 262144;                      // 8 MB (16*4*2048*16)
    float*  SUMP  = SUMH + 2097152;                   // 8 MB
    ushort* Yp    = XI;

    const dim3 blk(256);

    // 0) conversions
    cvt_bf16_kernel<<<dim3(8192), blk, 0, stream>>>(x, XP);
    split_w_kernel<<<dim3(4096), blk, 0, stream>>>(in_proj_w, WINH, WINL);
    split_w_kernel<<<dim3(4096), blk, 0, stream>>>(dt_proj_w, WDTH, WDTL);
    split_w_kernel<<<dim3(2048), blk, 0, stream>>>(out_proj_w, WOUTH, WOUTL);

    // 1) xi, z
    gemm_mfma<2><<<dim3(16, 64), blk, 0, stream>>>(XP, WINH, WINL, nullptr, XI, 2048, 1024);
    gemm_mfma<2><<<dim3(16, 64), blk, 0, stream>>>(XP, WINH + 2097152, WINL + 2097152,
                                                   nullptr, Z, 2048, 1024);

    // 2) xc = silu(conv(xi) + b)
    conv_silu_kernel<<<dim3(16384), blk, 0, stream>>>(XI, conv_w, conv_b, XC2);

    // 3) delta = softplus(xc @ Wdt^T + b)
    gemm_mfma<1><<<dim3(16, 64), blk, 0, stream>>>(XC2, WDTH, WDTL, dt_proj_b, DELTA, 2048, 2048);

    // 4) bc = xc @ x_proj_w^T
    gemm_bc_kernel<<<dim3(1, 64), blk, 0, stream>>>(XC2, x_proj_w, BC);

    // 5) chunked scan: pass1 (chunks 0..14) then pass2 (all 16)
    scan_part1<<<dim3((NCHK - 1) * 32), blk, 0, stream>>>(XC2, DELTA, BC, A_log, SUMH, SUMP);
    scan_part2<<<dim3(NCHK * 32), blk, 0, stream>>>(Z, XC2, DELTA, BC, A_log, Dp,
                                                    SUMH, SUMP, Yp);

    // 6) out = y @ Wout^T
    gemm_mfma<0><<<dim3(8, 64), blk, 0, stream>>>(Yp, WOUTH, WOUTL, nullptr, out, 1024, 2048);
}

// Round 7
// 717.556 us; speedup vs baseline: 5.4689x; 1.3813x over previous
//
#include <hip/hip_runtime.h>
#include <hip/hip_bf16.h>

// MambaMinimalBlock: B=4, L=2048, D_MODEL=1024, D_STATE=16, D_CONV=4,
// D_INNER=2048, BL=8192. fp32 in/out.
//
// GEMMs: bf16 MFMA, weight-split (W = Whi + Wlo), bf16 activations.
// Scan: d-parallel chunked 2-pass (R6: one lane per channel, h[16] in VGPRs).
// bc GEMM (R7): split-K MFMA (8 K-slices x 64 M-blocks = 512 blocks) +
// tiny reduce. R6's single-M-grid fp32 version had 64 blocks -> 3% occupancy,
// 290 us for ~6 us of roofline work.
//
// Workspace (~226 MB of 256 MiB):
//   XI/Z/XC2 bf16 32MB each | DELTA f32 64MB (first 16MB hosts X' bf16)
//   W planes 40MB | BC f32 1MB | SUMH/SUMP 8MB each | XPH/XPL 128KB each
//   PART f32 8MB

typedef float  f32x4  __attribute__((ext_vector_type(4)));
typedef short  bf16x8 __attribute__((ext_vector_type(8)));

#define NCHK 16
#define CLEN 128
#define SW   8      // scan window (double-buffered)

__device__ __forceinline__ ushort f2bf(float f) {
    uint u = __float_as_uint(f);
    u += 0x7FFF + ((u >> 16) & 1);          // RNE
    return (ushort)(u >> 16);
}
__device__ __forceinline__ float bf2f(ushort h) {
    return __uint_as_float((uint)h << 16);
}
__device__ __forceinline__ float softplus_f(float x) {
    return fmaxf(x, 0.f) + __logf(1.f + __expf(-fabsf(x)));
}
__device__ __forceinline__ float silu_f(float x) {
    return x / (1.f + __expf(-x));
}

__global__ __launch_bounds__(256)
void split_w_kernel(const float* __restrict__ src, ushort* __restrict__ hi,
                    ushort* __restrict__ lo)
{
    const int i = blockIdx.x * 256 + threadIdx.x;
    float4 v = ((const float4*)src)[i];
    ushort4 h, l;
    h.x = f2bf(v.x); l.x = f2bf(v.x - bf2f(h.x));
    h.y = f2bf(v.y); l.y = f2bf(v.y - bf2f(h.y));
    h.z = f2bf(v.z); l.z = f2bf(v.z - bf2f(h.z));
    h.w = f2bf(v.w); l.w = f2bf(v.w - bf2f(h.w));
    ((ushort4*)hi)[i] = h;
    ((ushort4*)lo)[i] = l;
}

__global__ __launch_bounds__(256)
void cvt_bf16_kernel(const float* __restrict__ src, ushort* __restrict__ dst)
{
    const int i = blockIdx.x * 256 + threadIdx.x;
    float4 v = ((const float4*)src)[i];
    ushort4 h;
    h.x = f2bf(v.x); h.y = f2bf(v.y); h.z = f2bf(v.z); h.w = f2bf(v.w);
    ((ushort4*)dst)[i] = h;
}

// C[M,N] = A[M,K](bf16) * (Bh+Bl)[N,K]^T (bf16 planes), fp32 accumulate.
// EPI: 0 = fp32 store, 1 = softplus(v + bias[col]) fp32, 2 = bf16 store.
template <int EPI>
__global__ __launch_bounds__(256)
void gemm_mfma(const ushort* __restrict__ A, const ushort* __restrict__ Bh,
               const ushort* __restrict__ Bl, const float* __restrict__ bias,
               void* __restrict__ Cout, int N, int K)
{
    __shared__ ushort As[4096];
    __shared__ ushort Bhs[4096];
    __shared__ ushort Bls[4096];

    const int tid  = threadIdx.x;
    const int lane = tid & 63;
    const int wave = tid >> 6;
    const int wm   = (wave >> 1) * 64;
    const int wn   = (wave & 1) * 64;
    const int row0 = blockIdx.y * 128;
    const int col0 = blockIdx.x * 128;

    const int crow   = tid >> 2;
    const int cpiece = (tid & 3) * 8;
    const ushort* Ag0 = A  + (size_t)(row0 + crow) * K + cpiece;
    const ushort* Ag1 = A  + (size_t)(row0 + crow + 64) * K + cpiece;
    const ushort* Bg0 = Bh + (size_t)(col0 + crow) * K + cpiece;
    const ushort* Bg1 = Bh + (size_t)(col0 + crow + 64) * K + cpiece;
    const ushort* Cg0 = Bl + (size_t)(col0 + crow) * K + cpiece;
    const ushort* Cg1 = Bl + (size_t)(col0 + crow + 64) * K + cpiece;
    const int lds_off = tid * 8;

    const int fq  = (lane >> 4) * 8;
    const int fra = (wm + (lane & 15)) * 32 + fq;
    const int frb = (wn + (lane & 15)) * 32 + fq;

    f32x4 acc[4][4];
#pragma unroll
    for (int mi = 0; mi < 4; ++mi)
#pragma unroll
        for (int ni = 0; ni < 4; ++ni)
            acc[mi][ni] = (f32x4){0.f, 0.f, 0.f, 0.f};

    uint4 ra0 = *(const uint4*)Ag0, ra1 = *(const uint4*)Ag1;
    uint4 rh0 = *(const uint4*)Bg0, rh1 = *(const uint4*)Bg1;
    uint4 rl0 = *(const uint4*)Cg0, rl1 = *(const uint4*)Cg1;

    for (int k0 = 0; k0 < K; k0 += 32) {
        __syncthreads();
        *(uint4*)(As  + lds_off)        = ra0;
        *(uint4*)(As  + lds_off + 2048) = ra1;
        *(uint4*)(Bhs + lds_off)        = rh0;
        *(uint4*)(Bhs + lds_off + 2048) = rh1;
        *(uint4*)(Bls + lds_off)        = rl0;
        *(uint4*)(Bls + lds_off + 2048) = rl1;
        __syncthreads();
        if (k0 + 32 < K) {
            ra0 = *(const uint4*)(Ag0 + k0 + 32);
            ra1 = *(const uint4*)(Ag1 + k0 + 32);
            rh0 = *(const uint4*)(Bg0 + k0 + 32);
            rh1 = *(const uint4*)(Bg1 + k0 + 32);
            rl0 = *(const uint4*)(Cg0 + k0 + 32);
            rl1 = *(const uint4*)(Cg1 + k0 + 32);
        }
        bf16x8 af[4], bh[4], bl[4];
#pragma unroll
        for (int mi = 0; mi < 4; ++mi)
            af[mi] = *(const bf16x8*)(As + fra + mi * 512);
#pragma unroll
        for (int ni = 0; ni < 4; ++ni) {
            bh[ni] = *(const bf16x8*)(Bhs + frb + ni * 512);
            bl[ni] = *(const bf16x8*)(Bls + frb + ni * 512);
        }
#pragma unroll
        for (int mi = 0; mi < 4; ++mi)
#pragma unroll
            for (int ni = 0; ni < 4; ++ni) {
                acc[mi][ni] = __builtin_amdgcn_mfma_f32_16x16x32_bf16(
                    af[mi], bh[ni], acc[mi][ni], 0, 0, 0);
                acc[mi][ni] = __builtin_amdgcn_mfma_f32_16x16x32_bf16(
                    af[mi], bl[ni], acc[mi][ni], 0, 0, 0);
            }
    }

#pragma unroll
    for (int mi = 0; mi < 4; ++mi) {
        const int rg = row0 + wm + mi * 16 + (lane >> 4) * 4;
#pragma unroll
        for (int ni = 0; ni < 4; ++ni) {
            const int cg = col0 + wn + ni * 16 + (lane & 15);
            f32x4 v = acc[mi][ni];
            if (EPI == 1) {
                const float bv = bias[cg];
#pragma unroll
                for (int r = 0; r < 4; ++r) v[r] = softplus_f(v[r] + bv);
            }
#pragma unroll
            for (int r = 0; r < 4; ++r) {
                if (EPI == 2)
                    ((ushort*)Cout)[(size_t)(rg + r) * N + cg] = f2bf(v[r]);
                else
                    ((float*)Cout)[(size_t)(rg + r) * N + cg] = v[r];
            }
        }
    }
}

// Split-K bc GEMM: part[ks] = xc[:, ks*256:(ks+1)*256] @ Wx^T slice.
// M=8192, N=32, K-slice=256. Grid (8, 64); same verified MFMA structure
// as gemm_mfma, shrunk to N=32 (per wave 32x32 via 2x2 tiles).
__global__ __launch_bounds__(256)
void gemm_bc_mfma(const ushort* __restrict__ A, const ushort* __restrict__ Bh,
                  const ushort* __restrict__ Bl, float* __restrict__ part)
{
    __shared__ ushort As[4096];      // 128 rows x 32 k
    __shared__ ushort Bhs[1024];     // 32 x 32
    __shared__ ushort Bls[1024];

    const int tid  = threadIdx.x;
    const int lane = tid & 63;
    const int wave = tid >> 6;
    const int ks   = blockIdx.x;     // 0..7
    const int mb   = blockIdx.y;     // 0..63
    const int row0 = mb * 128;
    const int kb   = ks * 256;

    const int crow   = tid >> 2;
    const int cpiece = (tid & 3) * 8;
    const ushort* Ag0 = A + (size_t)(row0 + crow) * 2048 + kb + cpiece;
    const ushort* Ag1 = A + (size_t)(row0 + crow + 64) * 2048 + kb + cpiece;

    const int t2     = tid & 127;
    const int brow   = t2 >> 2;      // 0..31
    const int bpiece = (t2 & 3) * 8;
    const ushort* Bg = (tid < 128 ? Bh : Bl) + (size_t)brow * 2048 + kb + bpiece;
    ushort* Bdst     = (tid < 128 ? Bhs : Bls) + t2 * 8;

    const int fq  = (lane >> 4) * 8;
    const int wm  = wave * 32;
    const int fra = (wm + (lane & 15)) * 32 + fq;
    const int frb = (lane & 15) * 32 + fq;

    f32x4 acc[2][2];
#pragma unroll
    for (int mi = 0; mi < 2; ++mi)
#pragma unroll
        for (int ni = 0; ni < 2; ++ni)
            acc[mi][ni] = (f32x4){0.f, 0.f, 0.f, 0.f};

    uint4 ra0 = *(const uint4*)Ag0, ra1 = *(const uint4*)Ag1;
    uint4 rb  = *(const uint4*)Bg;

    for (int kt = 0; kt < 8; ++kt) {
        __syncthreads();
        *(uint4*)(As + tid * 8)        = ra0;
        *(uint4*)(As + tid * 8 + 2048) = ra1;
        *(uint4*)Bdst = rb;
        __syncthreads();
        if (kt < 7) {
            ra0 = *(const uint4*)(Ag0 + (kt + 1) * 32);
            ra1 = *(const uint4*)(Ag1 + (kt + 1) * 32);
            rb  = *(const uint4*)(Bg + (kt + 1) * 32);
        }
        bf16x8 af[2], bhf[2], blf[2];
#pragma unroll
        for (int mi = 0; mi < 2; ++mi)
            af[mi] = *(const bf16x8*)(As + fra + mi * 512);
#pragma unroll
        for (int ni = 0; ni < 2; ++ni) {
            bhf[ni] = *(const bf16x8*)(Bhs + frb + ni * 512);
            blf[ni] = *(const bf16x8*)(Bls + frb + ni * 512);
        }
#pragma unroll
        for (int mi = 0; mi < 2; ++mi)
#pragma unroll
            for (int ni = 0; ni < 2; ++ni) {
                acc[mi][ni] = __builtin_amdgcn_mfma_f32_16x16x32_bf16(
                    af[mi], bhf[ni], acc[mi][ni], 0, 0, 0);
                acc[mi][ni] = __builtin_amdgcn_mfma_f32_16x16x32_bf16(
                    af[mi], blf[ni], acc[mi][ni], 0, 0, 0);
            }
    }

#pragma unroll
    for (int mi = 0; mi < 2; ++mi) {
        const int rg = row0 + wm + mi * 16 + (lane >> 4) * 4;
#pragma unroll
        for (int ni = 0; ni < 2; ++ni) {
            const int cg = ni * 16 + (lane & 15);
            f32x4 v = acc[mi][ni];
#pragma unroll
            for (int r = 0; r < 4; ++r)
                part[((size_t)ks * 8192 + rg + r) * 32 + cg] = v[r];
        }
    }
}

__global__ __launch_bounds__(256)
void bc_reduce_kernel(const float* __restrict__ part, float* __restrict__ bc)
{
    const int i = blockIdx.x * 256 + threadIdx.x;   // 262144
    float s = 0.f;
#pragma unroll
    for (int ks = 0; ks < 8; ++ks)
        s += part[(size_t)ks * 262144 + i];
    bc[i] = s;
}

// Depthwise causal conv1d (4 taps) + bias + silu; bf16 in, bf16 out.
__global__ __launch_bounds__(256)
void conv_silu_kernel(const ushort* __restrict__ xi, const float* __restrict__ cw,
                      const float* __restrict__ cb, ushort* __restrict__ xc)
{
    const int idx = blockIdx.x * 256 + threadIdx.x;
    const int e   = (idx & 511) << 2;
    const int row = idx >> 9;
    const int l   = row & 2047;

    const float4 w0 = *(const float4*)(cw + (size_t)(e + 0) * 4);
    const float4 w1 = *(const float4*)(cw + (size_t)(e + 1) * 4);
    const float4 w2 = *(const float4*)(cw + (size_t)(e + 2) * 4);
    const float4 w3 = *(const float4*)(cw + (size_t)(e + 3) * 4);

    float4 acc = *(const float4*)(cb + e);

#define CONV_TAP(K_, WSEL)                                                  \
    {                                                                       \
        ushort4 t = *(const ushort4*)(xi + (size_t)(row - (K_)) * 2048 + e);\
        acc.x = fmaf(bf2f(t.x), w0.WSEL, acc.x);                            \
        acc.y = fmaf(bf2f(t.y), w1.WSEL, acc.y);                            \
        acc.z = fmaf(bf2f(t.z), w2.WSEL, acc.z);                            \
        acc.w = fmaf(bf2f(t.w), w3.WSEL, acc.w);                            \
    }
    if (l >= 3) CONV_TAP(3, x)
    if (l >= 2) CONV_TAP(2, y)
    if (l >= 1) CONV_TAP(1, z)
    CONV_TAP(0, w)
#undef CONV_TAP

    ushort4 o;
    o.x = f2bf(silu_f(acc.x)); o.y = f2bf(silu_f(acc.y));
    o.z = f2bf(silu_f(acc.z)); o.w = f2bf(silu_f(acc.w));
    *(ushort4*)(xc + (size_t)row * 2048 + e) = o;
}

// ---- d-parallel chunked selective scan ----

// Pass 1: chunks 0..NCHK-2, h from 0, writes he + P = exp(A * sum dt).
__global__ __launch_bounds__(256)
void scan_part1(const ushort* __restrict__ xcb, const float* __restrict__ dbuf,
                const float* __restrict__ bcbuf, const float* __restrict__ A_log,
                float* __restrict__ sum_h, float* __restrict__ sum_p)
{
    const int c    = blockIdx.x >> 5;          // 0..14
    const int b    = (blockIdx.x >> 3) & 3;
    const int dblk = blockIdx.x & 7;
    const int d    = dblk * 256 + threadIdx.x;

    float Aval[16];
#pragma unroll
    for (int q = 0; q < 4; ++q) {
        float4 al = *(const float4*)(A_log + (size_t)d * 16 + q * 4);
        Aval[q*4+0] = -__expf(al.x); Aval[q*4+1] = -__expf(al.y);
        Aval[q*4+2] = -__expf(al.z); Aval[q*4+3] = -__expf(al.w);
    }

    const size_t row0 = (size_t)b * 2048 + (size_t)c * CLEN;
    const float*  dp  = dbuf + row0 * 2048 + d;
    const ushort* xp  = xcb  + row0 * 2048 + d;
    const float*  bcp = bcbuf + row0 * 32;

    float h[16];
#pragma unroll
    for (int s = 0; s < 16; ++s) h[s] = 0.f;
    float S = 0.f;

    float wdt[SW], wxv[SW];
#pragma unroll
    for (int j = 0; j < SW; ++j) {
        wdt[j] = dp[(size_t)j * 2048];
        wxv[j] = bf2f(xp[(size_t)j * 2048]);
    }
    float curB[16];
#pragma unroll
    for (int q = 0; q < 4; ++q)
        *(float4*)&curB[q*4] = *(const float4*)(bcp + q * 4);

    for (int l0 = 0; l0 < CLEN; l0 += SW) {
        float ndt[SW], nxv[SW];
        const bool more = (l0 + SW) < CLEN;
        if (more) {
#pragma unroll
            for (int j = 0; j < SW; ++j) {
                const size_t o = (size_t)(l0 + SW + j);
                ndt[j] = dp[o * 2048];
                nxv[j] = bf2f(xp[o * 2048]);
            }
        }
#pragma unroll
        for (int j = 0; j < SW; ++j) {
            const int l = l0 + j;
            float nB[16];
            if (l + 1 < CLEN) {
#pragma unroll
                for (int q = 0; q < 4; ++q)
                    *(float4*)&nB[q*4] = *(const float4*)(bcp + (size_t)(l+1) * 32 + q * 4);
            }
            const float dt = wdt[j];
            const float t  = dt * wxv[j];
            S += dt;
#pragma unroll
            for (int s = 0; s < 16; ++s)
                h[s] = __expf(dt * Aval[s]) * h[s] + curB[s] * t;
            if (l + 1 < CLEN) {
#pragma unroll
                for (int s = 0; s < 16; ++s) curB[s] = nB[s];
            }
        }
        if (more) {
#pragma unroll
            for (int j = 0; j < SW; ++j) { wdt[j] = ndt[j]; wxv[j] = nxv[j]; }
        }
    }

    float* sh = sum_h + ((((size_t)c * 4 + b) * 2048 + d) << 4);
    float* sp = sum_p + ((((size_t)c * 4 + b) * 2048 + d) << 4);
#pragma unroll
    for (int q = 0; q < 4; ++q) {
        *(float4*)(sh + q * 4) = make_float4(h[q*4], h[q*4+1], h[q*4+2], h[q*4+3]);
        *(float4*)(sp + q * 4) = make_float4(__expf(Aval[q*4] * S), __expf(Aval[q*4+1] * S),
                                             __expf(Aval[q*4+2] * S), __expf(Aval[q*4+3] * S));
    }
}

// Pass 2: all NCHK chunks; fold preceding summaries, scan, y bf16 out.
__global__ __launch_bounds__(256)
void scan_part2(const ushort* __restrict__ zbuf, const ushort* __restrict__ xcb,
                const float* __restrict__ dbuf, const float* __restrict__ bcbuf,
                const float* __restrict__ A_log, const float* __restrict__ Dp,
                const float* __restrict__ sum_h, const float* __restrict__ sum_p,
                ushort* __restrict__ ybuf)
{
    const int c    = blockIdx.x >> 5;          // 0..15
    const int b    = (blockIdx.x >> 3) & 3;
    const int dblk = blockIdx.x & 7;
    const int d    = dblk * 256 + threadIdx.x;

    float Aval[16];
#pragma unroll
    for (int q = 0; q < 4; ++q) {
        float4 al = *(const float4*)(A_log + (size_t)d * 16 + q * 4);
        Aval[q*4+0] = -__expf(al.x); Aval[q*4+1] = -__expf(al.y);
        Aval[q*4+2] = -__expf(al.z); Aval[q*4+3] = -__expf(al.w);
    }
    const float Dv = Dp[d];

    float h[16];
#pragma unroll
    for (int s = 0; s < 16; ++s) h[s] = 0.f;
    for (int j = 0; j < c; ++j) {              // fold chunk summaries
        const float* sh = sum_h + ((((size_t)j * 4 + b) * 2048 + d) << 4);
        const float* sp = sum_p + ((((size_t)j * 4 + b) * 2048 + d) << 4);
#pragma unroll
        for (int q = 0; q < 4; ++q) {
            float4 vh = *(const float4*)(sh + q * 4);
            float4 vp = *(const float4*)(sp + q * 4);
            h[q*4+0] = vh.x + vp.x * h[q*4+0];
            h[q*4+1] = vh.y + vp.y * h[q*4+1];
            h[q*4+2] = vh.z + vp.z * h[q*4+2];
            h[q*4+3] = vh.w + vp.w * h[q*4+3];
        }
    }

    const size_t row0 = (size_t)b * 2048 + (size_t)c * CLEN;
    const float*  dp  = dbuf + row0 * 2048 + d;
    const ushort* xp  = xcb  + row0 * 2048 + d;
    const ushort* zp  = zbuf + row0 * 2048 + d;
    const float*  bcp = bcbuf + row0 * 32;
    ushort*       yp  = ybuf + row0 * 2048 + d;

    float wdt[SW], wxv[SW], wzv[SW];
#pragma unroll
    for (int j = 0; j < SW; ++j) {
        wdt[j] = dp[(size_t)j * 2048];
        wxv[j] = bf2f(xp[(size_t)j * 2048]);
        wzv[j] = bf2f(zp[(size_t)j * 2048]);
    }
    float curB[16], curC[16];
#pragma unroll
    for (int q = 0; q < 4; ++q) {
        *(float4*)&curB[q*4] = *(const float4*)(bcp + q * 4);
        *(float4*)&curC[q*4] = *(const float4*)(bcp + 16 + q * 4);
    }

    for (int l0 = 0; l0 < CLEN; l0 += SW) {
        float ndt[SW], nxv[SW], nzv[SW];
        const bool more = (l0 + SW) < CLEN;
        if (more) {
#pragma unroll
            for (int j = 0; j < SW; ++j) {
                const size_t o = (size_t)(l0 + SW + j);
                ndt[j] = dp[o * 2048];
                nxv[j] = bf2f(xp[o * 2048]);
                nzv[j] = bf2f(zp[o * 2048]);
            }
        }
#pragma unroll
        for (int j = 0; j < SW; ++j) {
            const int l = l0 + j;
            float nB[16], nC[16];
            if (l + 1 < CLEN) {
#pragma unroll
                for (int q = 0; q < 4; ++q) {
                    *(float4*)&nB[q*4] = *(const float4*)(bcp + (size_t)(l+1) * 32 + q * 4);
                    *(float4*)&nC[q*4] = *(const float4*)(bcp + (size_t)(l+1) * 32 + 16 + q * 4);
                }
            }
            const float dt = wdt[j];
            const float t  = dt * wxv[j];
#pragma unroll
            for (int s = 0; s < 16; ++s)
                h[s] = __expf(dt * Aval[s]) * h[s] + curB[s] * t;
            float y0 = 0.f, y1 = 0.f, y2 = 0.f, y3 = 0.f;
#pragma unroll
            for (int s = 0; s < 16; s += 4) {
                y0 = fmaf(h[s+0], curC[s+0], y0);
                y1 = fmaf(h[s+1], curC[s+1], y1);
                y2 = fmaf(h[s+2], curC[s+2], y2);
                y3 = fmaf(h[s+3], curC[s+3], y3);
            }
            float y = (y0 + y1) + (y2 + y3) + Dv * wxv[j];
            yp[(size_t)l * 2048] = f2bf(y * silu_f(wzv[j]));
            if (l + 1 < CLEN) {
#pragma unroll
                for (int s = 0; s < 16; ++s) { curB[s] = nB[s]; curC[s] = nC[s]; }
            }
        }
        if (more) {
#pragma unroll
            for (int j = 0; j < SW; ++j) {
                wdt[j] = ndt[j]; wxv[j] = nxv[j]; wzv[j] = nzv[j];
            }
        }
    }
}

extern "C" void kernel_launch(void* const* d_in, const int* in_sizes, int n_in,
                              void* d_out, int out_size, void* d_ws, size_t ws_size,
                              hipStream_t stream)
{
    const float* x          = (const float*)d_in[0];
    const float* in_proj_w  = (const float*)d_in[1];
    const float* conv_w     = (const float*)d_in[2];
    const float* conv_b     = (const float*)d_in[3];
    const float* x_proj_w   = (const float*)d_in[4];
    const float* dt_proj_w  = (const float*)d_in[5];
    const float* dt_proj_b  = (const float*)d_in[6];
    const float* A_log      = (const float*)d_in[7];
    const float* Dp         = (const float*)d_in[8];
    const float* out_proj_w = (const float*)d_in[9];
    float* out = (float*)d_out;

    ushort* XI    = (ushort*)d_ws;                    // 32 MB; later Y'
    ushort* Z     = XI + 16777216;                    // 32 MB
    ushort* XC2   = Z + 16777216;                     // 32 MB
    float*  DELTA = (float*)(XC2 + 16777216);         // 64 MB
    ushort* XP    = (ushort*)DELTA;                   // x' bf16 (pre-DELTA)
    ushort* WINH  = (ushort*)(DELTA + 16777216);      // 8 MB
    ushort* WINL  = WINH + 4194304;                   // 8 MB
    ushort* WDTH  = WINL + 4194304;                   // 8 MB
    ushort* WDTL  = WDTH + 4194304;                   // 8 MB
    ushort* WOUTH = WDTL + 4194304;                   // 4 MB
    ushort* WOUTL = WOUTH + 2097152;                  // 4 MB
    float*  BC    = (float*)(WOUTL + 2097152);        // 1 MB
    float*  SUMH  = BC + 262144;                      // 8 MB
    float*  SUMP  = SUMH + 2097152;                   // 8 MB
    ushort* XPH   = (ushort*)(SUMP + 2097152);        // 128 KB (x_proj hi)
    ushort* XPL   = XPH + 65536;                      // 128 KB
    float*  PART  = (float*)(XPL + 65536);            // 8 MB split-K partials
    ushort* Yp    = XI;

    const dim3 blk(256);

    // 0) conversions
    cvt_bf16_kernel<<<dim3(8192), blk, 0, stream>>>(x, XP);
    split_w_kernel<<<dim3(4096), blk, 0, stream>>>(in_proj_w, WINH, WINL);
    split_w_kernel<<<dim3(4096), blk, 0, stream>>>(dt_proj_w, WDTH, WDTL);
    split_w_kernel<<<dim3(2048), blk, 0, stream>>>(out_proj_w, WOUTH, WOUTL);
    split_w_kernel<<<dim3(64),   blk, 0, stream>>>(x_proj_w, XPH, XPL);

    // 1) xi, z
    gemm_mfma<2><<<dim3(16, 64), blk, 0, stream>>>(XP, WINH, WINL, nullptr, XI, 2048, 1024);
    gemm_mfma<2><<<dim3(16, 64), blk, 0, stream>>>(XP, WINH + 2097152, WINL + 2097152,
                                                   nullptr, Z, 2048, 1024);

    // 2) xc = silu(conv(xi) + b)
    conv_silu_kernel<<<dim3(16384), blk, 0, stream>>>(XI, conv_w, conv_b, XC2);

    // 3) delta = softplus(xc @ Wdt^T + b)
    gemm_mfma<1><<<dim3(16, 64), blk, 0, stream>>>(XC2, WDTH, WDTL, dt_proj_b, DELTA, 2048, 2048);

    // 4) bc = xc @ x_proj_w^T  (split-K MFMA + reduce)
    gemm_bc_mfma<<<dim3(8, 64), blk, 0, stream>>>(XC2, XPH, XPL, PART);
    bc_reduce_kernel<<<dim3(1024), blk, 0, stream>>>(PART, BC);

    // 5) chunked scan: pass1 (chunks 0..14) then pass2 (all 16)
    scan_part1<<<dim3((NCHK - 1) * 32), blk, 0, stream>>>(XC2, DELTA, BC, A_log, SUMH, SUMP);
    scan_part2<<<dim3(NCHK * 32), blk, 0, stream>>>(Z, XC2, DELTA, BC, A_log, Dp,
                                                    SUMH, SUMP, Yp);

    // 6) out = y @ Wout^T
    gemm_mfma<0><<<dim3(8, 64), blk, 0, stream>>>(Yp, WOUTH, WOUTL, nullptr, out, 1024, 2048);
}